// Round 1
// baseline (1047.394 us; speedup 1.0000x reference)
//
#include <hip/hip_runtime.h>
#include <cstdint>

#define N_NODES 40000
#define N_EDGES 400000
#define DIN 256
#define DHID 128
#define NG 256
#define NHEAD 4
#define ETOT (N_EDGES + N_NODES)

// ---------------- CSR construction ----------------

__global__ void count_kernel(const int* __restrict__ dst, int* __restrict__ deg) {
    int i = blockIdx.x * 256 + threadIdx.x;
    if (i >= ETOT) return;
    int d = (i < N_EDGES) ? dst[i] : (i - N_EDGES);
    atomicAdd(&deg[d], 1);
}

__global__ void scan_kernel(const int* __restrict__ deg, int* __restrict__ offs,
                            int* __restrict__ cursor) {
    __shared__ int sdata[1024];
    __shared__ int carry_s;
    int t = threadIdx.x;
    if (t == 0) carry_s = 0;
    __syncthreads();
    const int nchunk = (N_NODES + 1023) / 1024;
    for (int c = 0; c < nchunk; c++) {
        int i = c * 1024 + t;
        int v = (i < N_NODES) ? deg[i] : 0;
        sdata[t] = v;
        __syncthreads();
        for (int off = 1; off < 1024; off <<= 1) {
            int add = (t >= off) ? sdata[t - off] : 0;
            __syncthreads();
            sdata[t] += add;
            __syncthreads();
        }
        int incl = sdata[t];
        int excl = incl - v;
        int carry = carry_s;
        if (i < N_NODES) { offs[i] = carry + excl; cursor[i] = carry + excl; }
        __syncthreads();
        if (t == 1023) carry_s = carry + incl;
        __syncthreads();
    }
    if (t == 0) offs[N_NODES] = carry_s;
}

__global__ void fill_kernel(const int* __restrict__ src, const int* __restrict__ dst,
                            int* __restrict__ cursor, int* __restrict__ csr) {
    int i = blockIdx.x * 256 + threadIdx.x;
    if (i >= ETOT) return;
    int s, d;
    if (i < N_EDGES) { s = src[i]; d = dst[i]; } else { s = d = i - N_EDGES; }
    int pos = atomicAdd(&cursor[d], 1);
    csr[pos] = s;
}

// ---------------- GEMM: C[M,Ncol] = A[M,K] * B[K,Ncol], fp32 ----------------
// M = N_NODES (multiple of 64), K multiple of 16, Ncol multiple of 64.

__global__ __launch_bounds__(256) void gemm_kernel(const float* __restrict__ A,
                                                   const float* __restrict__ B,
                                                   float* __restrict__ C,
                                                   int K, int Ncol) {
    __shared__ float As[16][65];
    __shared__ float Bs[16][65];
    int tid = threadIdx.x;
    int tx = tid & 15, ty = tid >> 4;
    int row0 = blockIdx.x * 64, col0 = blockIdx.y * 64;
    float acc[4][4] = {};
    for (int k0 = 0; k0 < K; k0 += 16) {
#pragma unroll
        for (int r = 0; r < 4; r++) {
            int idx = tid + r * 256;
            int m = idx >> 4, k = idx & 15;
            As[k][m] = A[(size_t)(row0 + m) * K + k0 + k];
        }
#pragma unroll
        for (int r = 0; r < 4; r++) {
            int idx = tid + r * 256;
            int kk = idx >> 6, c = idx & 63;
            Bs[kk][c] = B[(size_t)(k0 + kk) * Ncol + col0 + c];
        }
        __syncthreads();
#pragma unroll
        for (int k = 0; k < 16; k++) {
            float a[4], b[4];
#pragma unroll
            for (int i = 0; i < 4; i++) a[i] = As[k][ty * 4 + i];
#pragma unroll
            for (int j = 0; j < 4; j++) b[j] = Bs[k][tx * 4 + j];
#pragma unroll
            for (int i = 0; i < 4; i++)
#pragma unroll
                for (int j = 0; j < 4; j++) acc[i][j] += a[i] * b[j];
        }
        __syncthreads();
    }
#pragma unroll
    for (int i = 0; i < 4; i++)
#pragma unroll
        for (int j = 0; j < 4; j++)
            C[(size_t)(row0 + ty * 4 + i) * Ncol + col0 + tx * 4 + j] = acc[i][j];
}

// ---------------- per-node attention scores ----------------
// h row width = H*128. ssrc[n,h] = dot(h[n,h,:], asrc[h,:]), same for sdst.

template <int H>
__global__ void scores_kernel(const float* __restrict__ h, const float* __restrict__ asrc,
                              const float* __restrict__ adst, float* __restrict__ ssrc,
                              float* __restrict__ sdst) {
    const int W = H * 128;
    const int PER = W / 64;          // elems per lane
    const int GRP = 64 / H;          // lanes per head
    int wave = threadIdx.x >> 6, lane = threadIdx.x & 63;
    int node = blockIdx.x * (blockDim.x >> 6) + wave;
    if (node >= N_NODES) return;
    const float* row = h + (size_t)node * W + lane * PER;
    float ss = 0.f, sd = 0.f;
#pragma unroll
    for (int i = 0; i < PER; i++) {
        float hv = row[i];
        int e = lane * PER + i;
        ss += hv * asrc[e];
        sd += hv * adst[e];
    }
#pragma unroll
    for (int m = GRP >> 1; m >= 1; m >>= 1) {
        ss += __shfl_xor(ss, m, 64);
        sd += __shfl_xor(sd, m, 64);
    }
    if ((lane & (GRP - 1)) == 0) {
        int head = lane / GRP;
        ssrc[node * H + head] = ss;
        sdst[node * H + head] = sd;
    }
}

// ---------------- segment softmax + aggregation (fused epilogue) ----------------
// One block per dst node. H=4: 256 threads, wave=head, lane covers 2 channels.
// MODE 0: mean-over-heads + bias + ELU + BN -> outx[n,128]
// MODE 1 (H=1): + bias -> atomicAdd into pool[batch[n], 128]

template <int H, int MODE>
__global__ void agg_kernel(const int* __restrict__ offs, const int* __restrict__ csr,
                           const float* __restrict__ hbuf, const float* __restrict__ ssrc,
                           const float* __restrict__ sdst, const float* __restrict__ bias,
                           const float* __restrict__ bng, const float* __restrict__ bnb,
                           const float* __restrict__ bnm, const float* __restrict__ bnv,
                           float* __restrict__ outx, float* __restrict__ pool,
                           const int* __restrict__ batch) {
    __shared__ float lds[H * 128];
    int d = blockIdx.x;
    int wave = threadIdx.x >> 6, lane = threadIdx.x & 63;
    int hh = wave;
    int off = offs[d];
    int deg = offs[d + 1] - off;
    float sdv = sdst[d * H + hh];

    // pass 1: max
    float mmax = -1e30f;
    for (int j = lane; j < deg; j += 64) {
        int s = csr[off + j];
        float e = ssrc[s * H + hh] + sdv;
        e = e > 0.f ? e : 0.2f * e;
        mmax = fmaxf(mmax, e);
    }
#pragma unroll
    for (int m = 32; m >= 1; m >>= 1) mmax = fmaxf(mmax, __shfl_xor(mmax, m, 64));

    // pass 2: sum of exp
    float z = 0.f;
    for (int j = lane; j < deg; j += 64) {
        int s = csr[off + j];
        float e = ssrc[s * H + hh] + sdv;
        e = e > 0.f ? e : 0.2f * e;
        z += __expf(e - mmax);
    }
#pragma unroll
    for (int m = 32; m >= 1; m >>= 1) z += __shfl_xor(z, m, 64);
    float inv = 1.0f / (z + 1e-16f);

    // pass 3: weighted aggregation, lane covers channels 2*lane, 2*lane+1
    float accx = 0.f, accy = 0.f;
    for (int j = 0; j < deg; j++) {
        int s = csr[off + j];
        float e = ssrc[s * H + hh] + sdv;
        e = e > 0.f ? e : 0.2f * e;
        float alpha = __expf(e - mmax) * inv;
        const float2 hv = *(const float2*)(hbuf + (size_t)s * (H * 128) + hh * 128 + lane * 2);
        accx += alpha * hv.x;
        accy += alpha * hv.y;
    }

    if (MODE == 0) {
        lds[hh * 128 + lane * 2] = accx;
        lds[hh * 128 + lane * 2 + 1] = accy;
        __syncthreads();
        int c = threadIdx.x;
        if (c < 128) {
            float v = 0.f;
#pragma unroll
            for (int q = 0; q < H; q++) v += lds[q * 128 + c];
            v = v * (1.0f / H) + bias[c];
            v = v > 0.f ? v : (__expf(v) - 1.0f);                 // ELU
            float sc = bng[c] * rsqrtf(bnv[c] + 1e-5f);           // BN (eval)
            v = (v - bnm[c]) * sc + bnb[c];
            outx[(size_t)d * 128 + c] = v;
        }
    } else {
        int g = batch[d];
        atomicAdd(&pool[g * 128 + lane * 2], accx + bias[lane * 2]);
        atomicAdd(&pool[g * 128 + lane * 2 + 1], accy + bias[lane * 2 + 1]);
    }
}

__global__ void cnt_kernel(const int* __restrict__ batch, float* __restrict__ cnt) {
    int i = blockIdx.x * 256 + threadIdx.x;
    if (i >= N_NODES) return;
    atomicAdd(&cnt[batch[i]], 1.0f);
}

__global__ void final_kernel(const float* __restrict__ pool, const float* __restrict__ cnt,
                             float* __restrict__ out) {
    int i = blockIdx.x * 256 + threadIdx.x;
    if (i >= NG * DHID) return;
    out[i] = pool[i] / fmaxf(cnt[i / DHID], 1.0f);
}

// ---------------- host ----------------

extern "C" void kernel_launch(void* const* d_in, const int* in_sizes, int n_in,
                              void* d_out, int out_size, void* d_ws, size_t ws_size,
                              hipStream_t stream) {
    const float* x    = (const float*)d_in[0];
    const int* src    = (const int*)d_in[1];
    const int* dst    = (const int*)d_in[2];
    const int* batch  = (const int*)d_in[3];
    const float* W1   = (const float*)d_in[4];
    const float* as1  = (const float*)d_in[5];
    const float* ad1  = (const float*)d_in[6];
    const float* b1   = (const float*)d_in[7];
    const float* g1   = (const float*)d_in[8];
    const float* be1  = (const float*)d_in[9];
    const float* m1   = (const float*)d_in[10];
    const float* v1   = (const float*)d_in[11];
    const float* W2   = (const float*)d_in[12];
    const float* as2  = (const float*)d_in[13];
    const float* ad2  = (const float*)d_in[14];
    const float* b2   = (const float*)d_in[15];
    const float* g2   = (const float*)d_in[16];
    const float* be2  = (const float*)d_in[17];
    const float* m2   = (const float*)d_in[18];
    const float* v2   = (const float*)d_in[19];
    const float* W3   = (const float*)d_in[20];
    const float* as3  = (const float*)d_in[21];
    const float* ad3  = (const float*)d_in[22];
    const float* b3   = (const float*)d_in[23];
    float* out = (float*)d_out;

    char* w = (char*)d_ws;
    size_t o = 0;
    auto alloc = [&](size_t bytes) -> void* {
        void* p = w + o;
        o += (bytes + 255) & ~(size_t)255;
        return p;
    };
    int* deg     = (int*)alloc((size_t)N_NODES * 4);
    int* offs    = (int*)alloc((size_t)(N_NODES + 1) * 4);
    int* cursor  = (int*)alloc((size_t)N_NODES * 4);
    int* csr     = (int*)alloc((size_t)ETOT * 4);
    float* hbuf  = (float*)alloc((size_t)N_NODES * 512 * 4);
    float* ssrc  = (float*)alloc((size_t)N_NODES * NHEAD * 4);
    float* sdst  = (float*)alloc((size_t)N_NODES * NHEAD * 4);
    float* xbuf  = (float*)alloc((size_t)N_NODES * 128 * 4);
    float* pool  = (float*)alloc((size_t)NG * 128 * 4);
    float* cnt   = (float*)alloc((size_t)NG * 4);

    hipMemsetAsync(deg, 0, (size_t)N_NODES * 4, stream);
    hipMemsetAsync(pool, 0, (size_t)NG * 128 * 4, stream);
    hipMemsetAsync(cnt, 0, (size_t)NG * 4, stream);

    // CSR build (every call: inputs are re-poisoned/restored each launch)
    count_kernel<<<(ETOT + 255) / 256, 256, 0, stream>>>(dst, deg);
    scan_kernel<<<1, 1024, 0, stream>>>(deg, offs, cursor);
    fill_kernel<<<(ETOT + 255) / 256, 256, 0, stream>>>(src, dst, cursor, csr);

    // ----- layer 1: GAT(256 -> 4x128), mean heads, +b1, ELU, BN1 -----
    gemm_kernel<<<dim3(N_NODES / 64, 512 / 64), 256, 0, stream>>>(x, W1, hbuf, DIN, 512);
    scores_kernel<4><<<N_NODES / 4, 256, 0, stream>>>(hbuf, as1, ad1, ssrc, sdst);
    agg_kernel<4, 0><<<N_NODES, 256, 0, stream>>>(offs, csr, hbuf, ssrc, sdst, b1,
                                                  g1, be1, m1, v1, xbuf, nullptr, nullptr);

    // ----- layer 2: GAT(128 -> 4x128), mean heads, +b2, ELU, BN2 -----
    gemm_kernel<<<dim3(N_NODES / 64, 512 / 64), 256, 0, stream>>>(xbuf, W2, hbuf, DHID, 512);
    scores_kernel<4><<<N_NODES / 4, 256, 0, stream>>>(hbuf, as2, ad2, ssrc, sdst);
    agg_kernel<4, 0><<<N_NODES, 256, 0, stream>>>(offs, csr, hbuf, ssrc, sdst, b2,
                                                  g2, be2, m2, v2, xbuf, nullptr, nullptr);

    // ----- layer 3: GAT(128 -> 1x128), +b3, then pooled -----
    gemm_kernel<<<dim3(N_NODES / 64, 128 / 64), 256, 0, stream>>>(xbuf, W3, hbuf, DHID, 128);
    scores_kernel<1><<<N_NODES / 4, 256, 0, stream>>>(hbuf, as3, ad3, ssrc, sdst);
    cnt_kernel<<<(N_NODES + 255) / 256, 256, 0, stream>>>(batch, cnt);
    agg_kernel<1, 1><<<N_NODES, 64, 0, stream>>>(offs, csr, hbuf, ssrc, sdst, b3,
                                                 nullptr, nullptr, nullptr, nullptr,
                                                 nullptr, pool, batch);
    final_kernel<<<(NG * 128 + 255) / 256, 256, 0, stream>>>(pool, cnt, out);
}

// Round 2
// 776.626 us; speedup vs baseline: 1.3486x; 1.3486x over previous
//
#include <hip/hip_runtime.h>
#include <cstdint>

#define N_NODES 40000
#define N_EDGES 400000
#define DIN 256
#define DHID 128
#define NG 256
#define NHEAD 4
#define ETOT (N_EDGES + N_NODES)

typedef __attribute__((ext_vector_type(8))) short short8;
typedef __attribute__((ext_vector_type(4))) float floatx4;

static __device__ __forceinline__ unsigned short f2bf(float f) {
    unsigned u = __float_as_uint(f);
    unsigned r = (u + 0x7FFFu + ((u >> 16) & 1u)) >> 16;
    return (unsigned short)r;
}

// ---------------- CSR construction ----------------

__global__ void count_kernel(const int* __restrict__ dst, int* __restrict__ deg) {
    int i = blockIdx.x * 256 + threadIdx.x;
    if (i >= ETOT) return;
    int d = (i < N_EDGES) ? dst[i] : (i - N_EDGES);
    atomicAdd(&deg[d], 1);
}

__global__ void scan_kernel(const int* __restrict__ deg, int* __restrict__ offs,
                            int* __restrict__ cursor) {
    __shared__ int sdata[1024];
    __shared__ int carry_s;
    int t = threadIdx.x;
    if (t == 0) carry_s = 0;
    __syncthreads();
    const int nchunk = (N_NODES + 1023) / 1024;
    for (int c = 0; c < nchunk; c++) {
        int i = c * 1024 + t;
        int v = (i < N_NODES) ? deg[i] : 0;
        sdata[t] = v;
        __syncthreads();
        for (int off = 1; off < 1024; off <<= 1) {
            int add = (t >= off) ? sdata[t - off] : 0;
            __syncthreads();
            sdata[t] += add;
            __syncthreads();
        }
        int incl = sdata[t];
        int excl = incl - v;
        int carry = carry_s;
        if (i < N_NODES) { offs[i] = carry + excl; cursor[i] = carry + excl; }
        __syncthreads();
        if (t == 1023) carry_s = carry + incl;
        __syncthreads();
    }
    if (t == 0) offs[N_NODES] = carry_s;
}

__global__ void fill_kernel(const int* __restrict__ src, const int* __restrict__ dst,
                            int* __restrict__ cursor, int* __restrict__ csr) {
    int i = blockIdx.x * 256 + threadIdx.x;
    if (i >= ETOT) return;
    int s, d;
    if (i < N_EDGES) { s = src[i]; d = dst[i]; } else { s = d = i - N_EDGES; }
    int pos = atomicAdd(&cursor[d], 1);
    csr[pos] = s;
}

// ---------------- dtype prep ----------------

__global__ void cvt_bf16_kernel(const float* __restrict__ in, unsigned short* __restrict__ out,
                                int n) {
    int i = blockIdx.x * 256 + threadIdx.x;
    if (i >= n) return;
    out[i] = f2bf(in[i]);
}

// Wt[n*K + k] = bf16(W[k*N + n])
__global__ void transpose_w_kernel(const float* __restrict__ W, unsigned short* __restrict__ Wt,
                                   int K, int Nn) {
    int i = blockIdx.x * 256 + threadIdx.x;
    if (i >= K * Nn) return;
    int k = i / Nn, n = i - k * Nn;
    Wt[(size_t)n * K + k] = f2bf(W[i]);
}

// ---------------- MFMA GEMM ----------------
// C[M,NCOL] = A[M,K] * B[K,NCOL], A bf16 row-major, Bt[NCOL,K] bf16 (B transposed),
// C fp32. Block tile 64x128, 4 waves, wave = 64 rows x 32 cols (4x2 MFMA tiles).
// K chunked at 128. M % 64 == 0, NCOL % 128 == 0, K % 128 == 0.

template <int K, int NCOL>
__global__ __launch_bounds__(256) void mfma_gemm_kernel(const unsigned short* __restrict__ A,
                                                        const unsigned short* __restrict__ Bt,
                                                        float* __restrict__ C) {
    constexpr int KC = 128;
    constexpr int KP = KC + 8;   // padded LDS row stride (shorts)
    __shared__ alignas(16) unsigned short A_lds[64][KP];
    __shared__ alignas(16) unsigned short B_lds[128][KP];

    const int tid = threadIdx.x;
    const int lane = tid & 63, wave = tid >> 6;
    const int row0 = blockIdx.x * 64;
    const int col0 = blockIdx.y * 128;
    const int cq = lane & 15, rq = lane >> 4;   // frag col / quad

    floatx4 acc[4][2] = {};

    for (int k0 = 0; k0 < K; k0 += KC) {
        if (k0) __syncthreads();
        // stage A: 64 rows x 128 k  (16 slots of 8 shorts per row)
#pragma unroll
        for (int r = 0; r < 4; r++) {
            int i = r * 256 + tid;
            int row = i >> 4, slot = i & 15;
            short8 v = *(const short8*)(A + (size_t)(row0 + row) * K + k0 + slot * 8);
            *(short8*)&A_lds[row][slot * 8] = v;
        }
        // stage Bt: 128 cols x 128 k
#pragma unroll
        for (int r = 0; r < 8; r++) {
            int i = r * 256 + tid;
            int col = i >> 4, slot = i & 15;
            short8 v = *(const short8*)(Bt + (size_t)(col0 + col) * K + k0 + slot * 8);
            *(short8*)&B_lds[col][slot * 8] = v;
        }
        __syncthreads();

#pragma unroll
        for (int kk = 0; kk < KC; kk += 32) {
            short8 af[4], bf[2];
#pragma unroll
            for (int i = 0; i < 4; i++)
                af[i] = *(const short8*)&A_lds[i * 16 + cq][kk + rq * 8];
#pragma unroll
            for (int j = 0; j < 2; j++)
                bf[j] = *(const short8*)&B_lds[wave * 32 + j * 16 + cq][kk + rq * 8];
#pragma unroll
            for (int i = 0; i < 4; i++)
#pragma unroll
                for (int j = 0; j < 2; j++)
                    acc[i][j] = __builtin_amdgcn_mfma_f32_16x16x32_bf16(af[i], bf[j], acc[i][j], 0, 0, 0);
        }
    }

    // epilogue: C/D layout col=lane&15, row=rq*4+reg
#pragma unroll
    for (int i = 0; i < 4; i++)
#pragma unroll
        for (int j = 0; j < 2; j++) {
            float* cp = C + (size_t)(row0 + i * 16 + rq * 4) * NCOL + col0 + wave * 32 + j * 16 + cq;
#pragma unroll
            for (int r = 0; r < 4; r++)
                cp[(size_t)r * NCOL] = acc[i][j][r];
        }
}

// ---------------- per-node attention scores ----------------

template <int H>
__global__ void scores_kernel(const float* __restrict__ h, const float* __restrict__ asrc,
                              const float* __restrict__ adst, float* __restrict__ ssrc,
                              float* __restrict__ sdst) {
    const int W = H * 128;
    const int PER = W / 64;
    const int GRP = 64 / H;
    int wave = threadIdx.x >> 6, lane = threadIdx.x & 63;
    int node = blockIdx.x * (blockDim.x >> 6) + wave;
    if (node >= N_NODES) return;
    const float* row = h + (size_t)node * W + lane * PER;
    float ss = 0.f, sd = 0.f;
#pragma unroll
    for (int i = 0; i < PER; i++) {
        float hv = row[i];
        int e = lane * PER + i;
        ss += hv * asrc[e];
        sd += hv * adst[e];
    }
#pragma unroll
    for (int m = GRP >> 1; m >= 1; m >>= 1) {
        ss += __shfl_xor(ss, m, 64);
        sd += __shfl_xor(sd, m, 64);
    }
    if ((lane & (GRP - 1)) == 0) {
        int head = lane / GRP;
        ssrc[node * H + head] = ss;
        sdst[node * H + head] = sd;
    }
}

// ---------------- segment softmax + aggregation (fused epilogue) ----------------
// MODE 0: mean-over-heads + bias + ELU + BN -> outb[n,128] (bf16)
// MODE 1 (H=1): + bias -> atomicAdd into pool[batch[n], 128]

template <int H, int MODE>
__global__ void agg_kernel(const int* __restrict__ offs, const int* __restrict__ csr,
                           const float* __restrict__ hbuf, const float* __restrict__ ssrc,
                           const float* __restrict__ sdst, const float* __restrict__ bias,
                           const float* __restrict__ bng, const float* __restrict__ bnb,
                           const float* __restrict__ bnm, const float* __restrict__ bnv,
                           unsigned short* __restrict__ outb, float* __restrict__ pool,
                           const int* __restrict__ batch) {
    __shared__ float lds[H * 128];
    int d = blockIdx.x;
    int wave = threadIdx.x >> 6, lane = threadIdx.x & 63;
    int hh = wave;
    int off = offs[d];
    int deg = offs[d + 1] - off;
    float sdv = sdst[d * H + hh];

    float mmax = -1e30f;
    for (int j = lane; j < deg; j += 64) {
        int s = csr[off + j];
        float e = ssrc[s * H + hh] + sdv;
        e = e > 0.f ? e : 0.2f * e;
        mmax = fmaxf(mmax, e);
    }
#pragma unroll
    for (int m = 32; m >= 1; m >>= 1) mmax = fmaxf(mmax, __shfl_xor(mmax, m, 64));

    float z = 0.f;
    for (int j = lane; j < deg; j += 64) {
        int s = csr[off + j];
        float e = ssrc[s * H + hh] + sdv;
        e = e > 0.f ? e : 0.2f * e;
        z += __expf(e - mmax);
    }
#pragma unroll
    for (int m = 32; m >= 1; m >>= 1) z += __shfl_xor(z, m, 64);
    float inv = 1.0f / (z + 1e-16f);

    float accx = 0.f, accy = 0.f;
    for (int j = 0; j < deg; j++) {
        int s = csr[off + j];
        float e = ssrc[s * H + hh] + sdv;
        e = e > 0.f ? e : 0.2f * e;
        float alpha = __expf(e - mmax) * inv;
        const float2 hv = *(const float2*)(hbuf + (size_t)s * (H * 128) + hh * 128 + lane * 2);
        accx += alpha * hv.x;
        accy += alpha * hv.y;
    }

    if (MODE == 0) {
        lds[hh * 128 + lane * 2] = accx;
        lds[hh * 128 + lane * 2 + 1] = accy;
        __syncthreads();
        int c = threadIdx.x;
        if (c < 128) {
            float v = 0.f;
#pragma unroll
            for (int q = 0; q < H; q++) v += lds[q * 128 + c];
            v = v * (1.0f / H) + bias[c];
            v = v > 0.f ? v : (__expf(v) - 1.0f);                 // ELU
            float sc = bng[c] * rsqrtf(bnv[c] + 1e-5f);           // BN (eval)
            v = (v - bnm[c]) * sc + bnb[c];
            outb[(size_t)d * 128 + c] = f2bf(v);
        }
    } else {
        int g = batch[d];
        atomicAdd(&pool[g * 128 + lane * 2], accx + bias[lane * 2]);
        atomicAdd(&pool[g * 128 + lane * 2 + 1], accy + bias[lane * 2 + 1]);
    }
}

__global__ void cnt_kernel(const int* __restrict__ batch, float* __restrict__ cnt) {
    int i = blockIdx.x * 256 + threadIdx.x;
    if (i >= N_NODES) return;
    atomicAdd(&cnt[batch[i]], 1.0f);
}

__global__ void final_kernel(const float* __restrict__ pool, const float* __restrict__ cnt,
                             float* __restrict__ out) {
    int i = blockIdx.x * 256 + threadIdx.x;
    if (i >= NG * DHID) return;
    out[i] = pool[i] / fmaxf(cnt[i / DHID], 1.0f);
}

// ---------------- host ----------------

extern "C" void kernel_launch(void* const* d_in, const int* in_sizes, int n_in,
                              void* d_out, int out_size, void* d_ws, size_t ws_size,
                              hipStream_t stream) {
    const float* x    = (const float*)d_in[0];
    const int* src    = (const int*)d_in[1];
    const int* dst    = (const int*)d_in[2];
    const int* batch  = (const int*)d_in[3];
    const float* W1   = (const float*)d_in[4];
    const float* as1  = (const float*)d_in[5];
    const float* ad1  = (const float*)d_in[6];
    const float* b1   = (const float*)d_in[7];
    const float* g1   = (const float*)d_in[8];
    const float* be1  = (const float*)d_in[9];
    const float* m1   = (const float*)d_in[10];
    const float* v1   = (const float*)d_in[11];
    const float* W2   = (const float*)d_in[12];
    const float* as2  = (const float*)d_in[13];
    const float* ad2  = (const float*)d_in[14];
    const float* b2   = (const float*)d_in[15];
    const float* g2   = (const float*)d_in[16];
    const float* be2  = (const float*)d_in[17];
    const float* m2   = (const float*)d_in[18];
    const float* v2   = (const float*)d_in[19];
    const float* W3   = (const float*)d_in[20];
    const float* as3  = (const float*)d_in[21];
    const float* ad3  = (const float*)d_in[22];
    const float* b3   = (const float*)d_in[23];
    float* out = (float*)d_out;

    char* w = (char*)d_ws;
    size_t o = 0;
    auto alloc = [&](size_t bytes) -> void* {
        void* p = w + o;
        o += (bytes + 255) & ~(size_t)255;
        return p;
    };
    int* deg     = (int*)alloc((size_t)N_NODES * 4);
    int* offs    = (int*)alloc((size_t)(N_NODES + 1) * 4);
    int* cursor  = (int*)alloc((size_t)N_NODES * 4);
    int* csr     = (int*)alloc((size_t)ETOT * 4);
    float* hbuf  = (float*)alloc((size_t)N_NODES * 512 * 4);
    float* ssrc  = (float*)alloc((size_t)N_NODES * NHEAD * 4);
    float* sdst  = (float*)alloc((size_t)N_NODES * NHEAD * 4);
    float* pool  = (float*)alloc((size_t)NG * 128 * 4);
    float* cnt   = (float*)alloc((size_t)NG * 4);
    unsigned short* xb   = (unsigned short*)alloc((size_t)N_NODES * DIN * 2);
    unsigned short* xbuf = (unsigned short*)alloc((size_t)N_NODES * 128 * 2);
    unsigned short* W1t  = (unsigned short*)alloc((size_t)512 * 256 * 2);
    unsigned short* W2t  = (unsigned short*)alloc((size_t)512 * 128 * 2);
    unsigned short* W3t  = (unsigned short*)alloc((size_t)128 * 128 * 2);

    hipMemsetAsync(deg, 0, (size_t)N_NODES * 4, stream);
    hipMemsetAsync(pool, 0, (size_t)NG * 128 * 4, stream);
    hipMemsetAsync(cnt, 0, (size_t)NG * 4, stream);

    // CSR build
    count_kernel<<<(ETOT + 255) / 256, 256, 0, stream>>>(dst, deg);
    scan_kernel<<<1, 1024, 0, stream>>>(deg, offs, cursor);
    fill_kernel<<<(ETOT + 255) / 256, 256, 0, stream>>>(src, dst, cursor, csr);

    // dtype prep
    cvt_bf16_kernel<<<(N_NODES * DIN + 255) / 256, 256, 0, stream>>>(x, xb, N_NODES * DIN);
    transpose_w_kernel<<<(256 * 512 + 255) / 256, 256, 0, stream>>>(W1, W1t, 256, 512);
    transpose_w_kernel<<<(128 * 512 + 255) / 256, 256, 0, stream>>>(W2, W2t, 128, 512);
    transpose_w_kernel<<<(128 * 128 + 255) / 256, 256, 0, stream>>>(W3, W3t, 128, 128);

    // ----- layer 1: GAT(256 -> 4x128), mean heads, +b1, ELU, BN1 -----
    mfma_gemm_kernel<256, 512><<<dim3(N_NODES / 64, 4), 256, 0, stream>>>(xb, W1t, hbuf);
    scores_kernel<4><<<N_NODES / 4, 256, 0, stream>>>(hbuf, as1, ad1, ssrc, sdst);
    agg_kernel<4, 0><<<N_NODES, 256, 0, stream>>>(offs, csr, hbuf, ssrc, sdst, b1,
                                                  g1, be1, m1, v1, xbuf, nullptr, nullptr);

    // ----- layer 2: GAT(128 -> 4x128), mean heads, +b2, ELU, BN2 -----
    mfma_gemm_kernel<128, 512><<<dim3(N_NODES / 64, 4), 256, 0, stream>>>(xbuf, W2t, hbuf);
    scores_kernel<4><<<N_NODES / 4, 256, 0, stream>>>(hbuf, as2, ad2, ssrc, sdst);
    agg_kernel<4, 0><<<N_NODES, 256, 0, stream>>>(offs, csr, hbuf, ssrc, sdst, b2,
                                                  g2, be2, m2, v2, xbuf, nullptr, nullptr);

    // ----- layer 3: GAT(128 -> 1x128), +b3, then pooled -----
    mfma_gemm_kernel<128, 128><<<dim3(N_NODES / 64, 1), 256, 0, stream>>>(xbuf, W3t, hbuf);
    scores_kernel<1><<<N_NODES / 4, 256, 0, stream>>>(hbuf, as3, ad3, ssrc, sdst);
    cnt_kernel<<<(N_NODES + 255) / 256, 256, 0, stream>>>(batch, cnt);
    agg_kernel<1, 1><<<N_NODES, 64, 0, stream>>>(offs, csr, hbuf, ssrc, sdst, b3,
                                                 nullptr, nullptr, nullptr, nullptr,
                                                 nullptr, pool, batch);
    final_kernel<<<(NG * 128 + 255) / 256, 256, 0, stream>>>(pool, cnt, out);
}

// Round 4
// 753.524 us; speedup vs baseline: 1.3900x; 1.0307x over previous
//
#include <hip/hip_runtime.h>
#include <cstdint>

#define N_NODES 40000
#define N_EDGES 400000
#define DIN 256
#define DHID 128
#define NG 256
#define NHEAD 4
#define ETOT (N_EDGES + N_NODES)

typedef __attribute__((ext_vector_type(8))) short short8;
typedef __attribute__((ext_vector_type(8))) unsigned short bfx8;
typedef __attribute__((ext_vector_type(4))) unsigned short bfx4;
typedef __attribute__((ext_vector_type(2))) unsigned short bfx2;
typedef __attribute__((ext_vector_type(4))) float floatx4;

static __device__ __forceinline__ unsigned short f2bf(float f) {
    unsigned u = __float_as_uint(f);
    unsigned r = (u + 0x7FFFu + ((u >> 16) & 1u)) >> 16;
    return (unsigned short)r;
}
static __device__ __forceinline__ float bf2f(unsigned short s) {
    return __uint_as_float((unsigned)s << 16);
}

// ---------------- CSR construction ----------------

__global__ void count_kernel(const int* __restrict__ dst, int* __restrict__ deg) {
    int i = blockIdx.x * 256 + threadIdx.x;
    if (i >= ETOT) return;
    int d = (i < N_EDGES) ? dst[i] : (i - N_EDGES);
    atomicAdd(&deg[d], 1);
}

// 1024 threads, 40 values/thread, wave-shuffle scan: 2 barriers total.
__global__ __launch_bounds__(1024) void scan_kernel(const int* __restrict__ deg,
                                                    int* __restrict__ offs,
                                                    int* __restrict__ cursor) {
    const int VPT = 40;  // 1024*40 = 40960 >= 40000
    __shared__ int wsum[16];
    int t = threadIdx.x;
    int lane = t & 63, wv = t >> 6;
    int base = t * VPT;
    int vals[VPT];
    int run = 0;
#pragma unroll
    for (int i = 0; i < VPT; i++) {
        int idx = base + i;
        int v = (idx < N_NODES) ? deg[idx] : 0;
        vals[i] = run;
        run += v;
    }
    int inc = run;
#pragma unroll
    for (int off = 1; off < 64; off <<= 1) {
        int n = __shfl_up(inc, off, 64);
        if (lane >= off) inc += n;
    }
    if (lane == 63) wsum[wv] = inc;
    __syncthreads();
    if (t == 0) {
        int c = 0;
#pragma unroll
        for (int i = 0; i < 16; i++) { int v = wsum[i]; wsum[i] = c; c += v; }
    }
    __syncthreads();
    int excl = wsum[wv] + inc - run;
#pragma unroll
    for (int i = 0; i < VPT; i++) {
        int idx = base + i;
        if (idx < N_NODES) { int o = excl + vals[i]; offs[idx] = o; cursor[idx] = o; }
    }
    if (t == 0) offs[N_NODES] = ETOT;   // degrees sum to ETOT by construction
}

__global__ void fill_kernel(const int* __restrict__ src, const int* __restrict__ dst,
                            int* __restrict__ cursor, int* __restrict__ csr) {
    int i = blockIdx.x * 256 + threadIdx.x;
    if (i >= ETOT) return;
    int s, d;
    if (i < N_EDGES) { s = src[i]; d = dst[i]; } else { s = d = i - N_EDGES; }
    int pos = atomicAdd(&cursor[d], 1);
    csr[pos] = s;
}

// ---------------- dtype prep ----------------

__global__ void cvt_bf16_kernel(const float* __restrict__ in, unsigned short* __restrict__ out,
                                int n) {
    int i = blockIdx.x * 256 + threadIdx.x;
    if (i >= n) return;
    out[i] = f2bf(in[i]);
}

__global__ void transpose_w_kernel(const float* __restrict__ W, unsigned short* __restrict__ Wt,
                                   int K, int Nn) {
    int i = blockIdx.x * 256 + threadIdx.x;
    if (i >= K * Nn) return;
    int k = i / Nn, n = i - k * Nn;
    Wt[(size_t)n * K + k] = f2bf(W[i]);
}

// ---------------- MFMA GEMM (bf16 in, bf16 out) ----------------
// C[M,NCOL] = A[M,K]*B[K,NCOL]; A bf16 row-major, Bt[NCOL,K] bf16; C bf16.
// Block tile 64x128, 4 waves (wave = 64 rows x 32 cols), K chunked 128.

template <int K, int NCOL>
__global__ __launch_bounds__(256) void mfma_gemm_kernel(const unsigned short* __restrict__ A,
                                                        const unsigned short* __restrict__ Bt,
                                                        unsigned short* __restrict__ C) {
    constexpr int KC = 128;
    constexpr int KP = KC + 8;
    __shared__ alignas(16) unsigned short A_lds[64][KP];
    __shared__ alignas(16) unsigned short B_lds[128][KP];

    const int tid = threadIdx.x;
    const int lane = tid & 63, wave = tid >> 6;
    const int row0 = blockIdx.x * 64;
    const int col0 = blockIdx.y * 128;
    const int cq = lane & 15, rq = lane >> 4;

    floatx4 acc[4][2] = {};

    for (int k0 = 0; k0 < K; k0 += KC) {
        if (k0) __syncthreads();
#pragma unroll
        for (int r = 0; r < 4; r++) {
            int i = r * 256 + tid;
            int row = i >> 4, slot = i & 15;
            short8 v = *(const short8*)(A + (size_t)(row0 + row) * K + k0 + slot * 8);
            *(short8*)&A_lds[row][slot * 8] = v;
        }
#pragma unroll
        for (int r = 0; r < 8; r++) {
            int i = r * 256 + tid;
            int col = i >> 4, slot = i & 15;
            short8 v = *(const short8*)(Bt + (size_t)(col0 + col) * K + k0 + slot * 8);
            *(short8*)&B_lds[col][slot * 8] = v;
        }
        __syncthreads();

#pragma unroll
        for (int kk = 0; kk < KC; kk += 32) {
            short8 af[4], bfr[2];
#pragma unroll
            for (int i = 0; i < 4; i++)
                af[i] = *(const short8*)&A_lds[i * 16 + cq][kk + rq * 8];
#pragma unroll
            for (int j = 0; j < 2; j++)
                bfr[j] = *(const short8*)&B_lds[wave * 32 + j * 16 + cq][kk + rq * 8];
#pragma unroll
            for (int i = 0; i < 4; i++)
#pragma unroll
                for (int j = 0; j < 2; j++)
                    acc[i][j] = __builtin_amdgcn_mfma_f32_16x16x32_bf16(af[i], bfr[j], acc[i][j], 0, 0, 0);
        }
    }

#pragma unroll
    for (int i = 0; i < 4; i++)
#pragma unroll
        for (int j = 0; j < 2; j++) {
            unsigned short* cp = C + (size_t)(row0 + i * 16 + rq * 4) * NCOL + col0 + wave * 32 + j * 16 + cq;
#pragma unroll
            for (int r = 0; r < 4; r++)
                cp[(size_t)r * NCOL] = f2bf(acc[i][j][r]);
        }
}

// ---------------- per-node attention scores (bf16 h) ----------------

template <int H>
__global__ void scores_kernel(const unsigned short* __restrict__ h,
                              const float* __restrict__ asrc,
                              const float* __restrict__ adst, float* __restrict__ ssrc,
                              float* __restrict__ sdst) {
    const int W = H * 128;
    const int PER = W / 64;
    const int GRP = 64 / H;
    int wave = threadIdx.x >> 6, lane = threadIdx.x & 63;
    int node = blockIdx.x * (blockDim.x >> 6) + wave;
    if (node >= N_NODES) return;
    const unsigned short* row = h + (size_t)node * W + lane * PER;
    float ss = 0.f, sd = 0.f;
    if (PER == 8) {
        bfx8 v = *(const bfx8*)row;
#pragma unroll
        for (int i = 0; i < 8; i++) {
            float hv = bf2f(v[i]);
            int e = lane * 8 + i;
            ss += hv * asrc[e];
            sd += hv * adst[e];
        }
    } else {
        bfx2 v = *(const bfx2*)row;
#pragma unroll
        for (int i = 0; i < PER; i++) {
            float hv = bf2f(v[i]);
            int e = lane * PER + i;
            ss += hv * asrc[e];
            sd += hv * adst[e];
        }
    }
#pragma unroll
    for (int m = GRP >> 1; m >= 1; m >>= 1) {
        ss += __shfl_xor(ss, m, 64);
        sd += __shfl_xor(sd, m, 64);
    }
    if ((lane & (GRP - 1)) == 0) {
        int head = lane / GRP;
        ssrc[node * H + head] = ss;
        sdst[node * H + head] = sd;
    }
}

// ---------------- segment softmax + aggregation ----------------
// MODE 0 (H=4): 256 thr, wave=head. pass3: half-waves take alternate edges,
//   each lane loads 4 bf16 channels (8 B). mean-heads + bias + ELU + BN -> bf16.
// MODE 1 (H=1): 64 thr. + bias -> atomicAdd pool[batch[d]].

template <int H, int MODE>
__global__ void agg_kernel(const int* __restrict__ offs, const int* __restrict__ csr,
                           const unsigned short* __restrict__ hbuf,
                           const float* __restrict__ ssrc,
                           const float* __restrict__ sdst, const float* __restrict__ bias,
                           const float* __restrict__ bng, const float* __restrict__ bnb,
                           const float* __restrict__ bnm, const float* __restrict__ bnv,
                           unsigned short* __restrict__ outb, float* __restrict__ pool,
                           const int* __restrict__ batch) {
    __shared__ float lds[H * 128];
    int d = blockIdx.x;
    int wave = threadIdx.x >> 6, lane = threadIdx.x & 63;
    int hh = wave;
    int off = offs[d];
    int deg = offs[d + 1] - off;
    float sdv = sdst[d * H + hh];

    // pass 1: max
    float mmax = -1e30f;
    for (int j = lane; j < deg; j += 64) {
        int s = csr[off + j];
        float e = ssrc[s * H + hh] + sdv;
        e = e > 0.f ? e : 0.2f * e;
        mmax = fmaxf(mmax, e);
    }
#pragma unroll
    for (int m = 32; m >= 1; m >>= 1) mmax = fmaxf(mmax, __shfl_xor(mmax, m, 64));

    // pass 2: sum of exp
    float z = 0.f;
    for (int j = lane; j < deg; j += 64) {
        int s = csr[off + j];
        float e = ssrc[s * H + hh] + sdv;
        e = e > 0.f ? e : 0.2f * e;
        z += __expf(e - mmax);
    }
#pragma unroll
    for (int m = 32; m >= 1; m >>= 1) z += __shfl_xor(z, m, 64);
    float inv = 1.0f / (z + 1e-16f);

    // pass 3: two edges per wave, 4 channels (8 B) per lane
    int half = lane >> 5, li = lane & 31;
    float acc[4] = {};
    for (int j = half; j < deg; j += 2) {
        int s = csr[off + j];
        float e = ssrc[s * H + hh] + sdv;
        e = e > 0.f ? e : 0.2f * e;
        float alpha = __expf(e - mmax) * inv;
        bfx4 hv = *(const bfx4*)(hbuf + (size_t)s * (H * 128) + hh * 128 + li * 4);
#pragma unroll
        for (int i = 0; i < 4; i++) acc[i] += alpha * bf2f(hv[i]);
    }
#pragma unroll
    for (int i = 0; i < 4; i++) acc[i] += __shfl_xor(acc[i], 32, 64);

    if (MODE == 0) {
        if (lane < 32) {
#pragma unroll
            for (int i = 0; i < 4; i++) lds[hh * 128 + li * 4 + i] = acc[i];
        }
        __syncthreads();
        int c = threadIdx.x;
        if (c < 128) {
            float v = 0.f;
#pragma unroll
            for (int q = 0; q < H; q++) v += lds[q * 128 + c];
            v = v * (1.0f / H) + bias[c];
            v = v > 0.f ? v : (__expf(v) - 1.0f);                 // ELU
            float sc = bng[c] * rsqrtf(bnv[c] + 1e-5f);           // BN (eval)
            v = (v - bnm[c]) * sc + bnb[c];
            outb[(size_t)d * 128 + c] = f2bf(v);
        }
    } else {
        if (lane < 32) {
            int g = batch[d];
#pragma unroll
            for (int i = 0; i < 4; i++)
                atomicAdd(&pool[g * 128 + li * 4 + i], acc[i] + bias[li * 4 + i]);
        }
    }
}

__global__ void cnt_kernel(const int* __restrict__ batch, float* __restrict__ cnt) {
    int i = blockIdx.x * 256 + threadIdx.x;
    if (i >= N_NODES) return;
    atomicAdd(&cnt[batch[i]], 1.0f);
}

__global__ void final_kernel(const float* __restrict__ pool, const float* __restrict__ cnt,
                             float* __restrict__ out) {
    int i = blockIdx.x * 256 + threadIdx.x;
    if (i >= NG * DHID) return;
    out[i] = pool[i] / fmaxf(cnt[i / DHID], 1.0f);
}

// ---------------- host ----------------

extern "C" void kernel_launch(void* const* d_in, const int* in_sizes, int n_in,
                              void* d_out, int out_size, void* d_ws, size_t ws_size,
                              hipStream_t stream) {
    const float* x    = (const float*)d_in[0];
    const int* src    = (const int*)d_in[1];
    const int* dst    = (const int*)d_in[2];
    const int* batch  = (const int*)d_in[3];
    const float* W1   = (const float*)d_in[4];
    const float* as1  = (const float*)d_in[5];
    const float* ad1  = (const float*)d_in[6];
    const float* b1   = (const float*)d_in[7];
    const float* g1   = (const float*)d_in[8];
    const float* be1  = (const float*)d_in[9];
    const float* m1   = (const float*)d_in[10];
    const float* v1   = (const float*)d_in[11];
    const float* W2   = (const float*)d_in[12];
    const float* as2  = (const float*)d_in[13];
    const float* ad2  = (const float*)d_in[14];
    const float* b2   = (const float*)d_in[15];
    const float* g2   = (const float*)d_in[16];
    const float* be2  = (const float*)d_in[17];
    const float* m2   = (const float*)d_in[18];
    const float* v2   = (const float*)d_in[19];
    const float* W3   = (const float*)d_in[20];
    const float* as3  = (const float*)d_in[21];
    const float* ad3  = (const float*)d_in[22];
    const float* b3   = (const float*)d_in[23];
    float* out = (float*)d_out;

    char* w = (char*)d_ws;
    size_t o = 0;
    auto alloc = [&](size_t bytes) -> void* {
        void* p = w + o;
        o += (bytes + 255) & ~(size_t)255;
        return p;
    };
    int* deg     = (int*)alloc((size_t)N_NODES * 4);
    int* offs    = (int*)alloc((size_t)(N_NODES + 1) * 4);
    int* cursor  = (int*)alloc((size_t)N_NODES * 4);
    int* csr     = (int*)alloc((size_t)ETOT * 4);
    float* ssrc  = (float*)alloc((size_t)N_NODES * NHEAD * 4);
    float* sdst  = (float*)alloc((size_t)N_NODES * NHEAD * 4);
    float* pool  = (float*)alloc((size_t)NG * 128 * 4);
    float* cnt   = (float*)alloc((size_t)NG * 4);
    unsigned short* hbuf = (unsigned short*)alloc((size_t)N_NODES * 512 * 2);
    unsigned short* xb   = (unsigned short*)alloc((size_t)N_NODES * DIN * 2);
    unsigned short* xbuf = (unsigned short*)alloc((size_t)N_NODES * 128 * 2);
    unsigned short* W1t  = (unsigned short*)alloc((size_t)512 * 256 * 2);
    unsigned short* W2t  = (unsigned short*)alloc((size_t)512 * 128 * 2);
    unsigned short* W3t  = (unsigned short*)alloc((size_t)128 * 128 * 2);

    (void)hipMemsetAsync(deg, 0, (size_t)N_NODES * 4, stream);
    (void)hipMemsetAsync(pool, 0, (size_t)NG * 128 * 4, stream);
    (void)hipMemsetAsync(cnt, 0, (size_t)NG * 4, stream);

    // CSR build
    count_kernel<<<(ETOT + 255) / 256, 256, 0, stream>>>(dst, deg);
    scan_kernel<<<1, 1024, 0, stream>>>(deg, offs, cursor);
    fill_kernel<<<(ETOT + 255) / 256, 256, 0, stream>>>(src, dst, cursor, csr);

    // dtype prep
    cvt_bf16_kernel<<<(N_NODES * DIN + 255) / 256, 256, 0, stream>>>(x, xb, N_NODES * DIN);
    transpose_w_kernel<<<(256 * 512 + 255) / 256, 256, 0, stream>>>(W1, W1t, 256, 512);
    transpose_w_kernel<<<(128 * 512 + 255) / 256, 256, 0, stream>>>(W2, W2t, 128, 512);
    transpose_w_kernel<<<(128 * 128 + 255) / 256, 256, 0, stream>>>(W3, W3t, 128, 128);

    // ----- layer 1 -----
    mfma_gemm_kernel<256, 512><<<dim3(N_NODES / 64, 4), 256, 0, stream>>>(xb, W1t, hbuf);
    scores_kernel<4><<<N_NODES / 4, 256, 0, stream>>>(hbuf, as1, ad1, ssrc, sdst);
    agg_kernel<4, 0><<<N_NODES, 256, 0, stream>>>(offs, csr, hbuf, ssrc, sdst, b1,
                                                  g1, be1, m1, v1, xbuf, nullptr, nullptr);

    // ----- layer 2 -----
    mfma_gemm_kernel<128, 512><<<dim3(N_NODES / 64, 4), 256, 0, stream>>>(xbuf, W2t, hbuf);
    scores_kernel<4><<<N_NODES / 4, 256, 0, stream>>>(hbuf, as2, ad2, ssrc, sdst);
    agg_kernel<4, 0><<<N_NODES, 256, 0, stream>>>(offs, csr, hbuf, ssrc, sdst, b2,
                                                  g2, be2, m2, v2, xbuf, nullptr, nullptr);

    // ----- layer 3 -----
    mfma_gemm_kernel<128, 128><<<dim3(N_NODES / 64, 1), 256, 0, stream>>>(xbuf, W3t, hbuf);
    scores_kernel<1><<<N_NODES / 4, 256, 0, stream>>>(hbuf, as3, ad3, ssrc, sdst);
    cnt_kernel<<<(N_NODES + 255) / 256, 256, 0, stream>>>(batch, cnt);
    agg_kernel<1, 1><<<N_NODES, 64, 0, stream>>>(offs, csr, hbuf, ssrc, sdst, b3,
                                                 nullptr, nullptr, nullptr, nullptr,
                                                 nullptr, pool, batch);
    final_kernel<<<(NG * 128 + 255) / 256, 256, 0, stream>>>(pool, cnt, out);
}

// Round 5
// 619.244 us; speedup vs baseline: 1.6914x; 1.2168x over previous
//
#include <hip/hip_runtime.h>
#include <cstdint>

#define N_NODES 40000
#define N_EDGES 400000
#define DIN 256
#define DHID 128
#define NG 256
#define NHEAD 4
#define ETOT (N_EDGES + N_NODES)

typedef __attribute__((ext_vector_type(8))) short short8;
typedef __attribute__((ext_vector_type(8))) unsigned short bfx8;
typedef __attribute__((ext_vector_type(4))) unsigned short bfx4;
typedef __attribute__((ext_vector_type(4))) float floatx4;

static __device__ __forceinline__ unsigned short f2bf(float f) {
    unsigned u = __float_as_uint(f);
    unsigned r = (u + 0x7FFFu + ((u >> 16) & 1u)) >> 16;
    return (unsigned short)r;
}
static __device__ __forceinline__ float bf2f(unsigned short s) {
    return __uint_as_float((unsigned)s << 16);
}

// ---------------- CSR construction ----------------

__global__ void count_kernel(const int* __restrict__ dst, int* __restrict__ deg,
                             const int* __restrict__ batch, float* __restrict__ cnt) {
    int i = blockIdx.x * 256 + threadIdx.x;
    if (i >= ETOT) return;
    int d = (i < N_EDGES) ? dst[i] : (i - N_EDGES);
    atomicAdd(&deg[d], 1);
    if (i < N_NODES) atomicAdd(&cnt[batch[i]], 1.0f);
}

__global__ __launch_bounds__(1024) void scan_kernel(const int* __restrict__ deg,
                                                    int* __restrict__ offs,
                                                    int* __restrict__ cursor) {
    const int VPT = 40;
    __shared__ int wsum[16];
    int t = threadIdx.x;
    int lane = t & 63, wv = t >> 6;
    int base = t * VPT;
    int vals[VPT];
    int run = 0;
#pragma unroll
    for (int i = 0; i < VPT; i++) {
        int idx = base + i;
        int v = (idx < N_NODES) ? deg[idx] : 0;
        vals[i] = run;
        run += v;
    }
    int inc = run;
#pragma unroll
    for (int off = 1; off < 64; off <<= 1) {
        int n = __shfl_up(inc, off, 64);
        if (lane >= off) inc += n;
    }
    if (lane == 63) wsum[wv] = inc;
    __syncthreads();
    if (t == 0) {
        int c = 0;
#pragma unroll
        for (int i = 0; i < 16; i++) { int v = wsum[i]; wsum[i] = c; c += v; }
    }
    __syncthreads();
    int excl = wsum[wv] + inc - run;
#pragma unroll
    for (int i = 0; i < VPT; i++) {
        int idx = base + i;
        if (idx < N_NODES) { int o = excl + vals[i]; offs[idx] = o; cursor[idx] = o; }
    }
    if (t == 0) offs[N_NODES] = ETOT;
}

__global__ void fill_kernel(const int* __restrict__ src, const int* __restrict__ dst,
                            int* __restrict__ cursor, int* __restrict__ csr,
                            int* __restrict__ dstp) {
    int i = blockIdx.x * 256 + threadIdx.x;
    if (i >= ETOT) return;
    int s, d;
    if (i < N_EDGES) { s = src[i]; d = dst[i]; } else { s = d = i - N_EDGES; }
    int pos = atomicAdd(&cursor[d], 1);
    csr[pos] = s;
    dstp[pos] = d;
}

// ---------------- dtype prep ----------------

__global__ void cvt_bf16_kernel(const float* __restrict__ in, unsigned short* __restrict__ out,
                                int n) {
    int i = blockIdx.x * 256 + threadIdx.x;
    if (i >= n) return;
    out[i] = f2bf(in[i]);
}

__global__ void transpose_w_kernel(const float* __restrict__ W, unsigned short* __restrict__ Wt,
                                   int K, int Nn) {
    int i = blockIdx.x * 256 + threadIdx.x;
    if (i >= K * Nn) return;
    int k = i / Nn, n = i - k * Nn;
    Wt[(size_t)n * K + k] = f2bf(W[i]);
}

// ---------------- MFMA GEMM + fused attention-score epilogue ----------------
// C[M,NCOL] = A[M,K]*Bt^T; A bf16, Bt[NCOL,K] bf16; C bf16.
// Block 64x128 (4 waves, wave = 64 rows x 32 cols). Each block's 128 cols are
// exactly one head -> epilogue computes ss/sd = dot(h_row, a_src/a_dst) for its
// 64 rows and writes ssrc/sdst[(row)*SH + head] (SH = NCOL/128 heads total).

template <int K, int NCOL>
__global__ __launch_bounds__(256) void mfma_gemm_kernel(const unsigned short* __restrict__ A,
                                                        const unsigned short* __restrict__ Bt,
                                                        unsigned short* __restrict__ C,
                                                        const float* __restrict__ asrc,
                                                        const float* __restrict__ adst,
                                                        float* __restrict__ ssrc,
                                                        float* __restrict__ sdst) {
    constexpr int KC = 128;
    constexpr int KP = KC + 8;
    constexpr int SH = NCOL / 128;
    __shared__ alignas(16) unsigned short A_lds[64][KP];
    __shared__ alignas(16) unsigned short B_lds[128][KP];

    const int tid = threadIdx.x;
    const int lane = tid & 63, wave = tid >> 6;
    const int row0 = blockIdx.x * 64;
    const int head = blockIdx.y;
    const int col0 = head * 128;
    const int cq = lane & 15, rq = lane >> 4;

    floatx4 acc[4][2] = {};

    for (int k0 = 0; k0 < K; k0 += KC) {
        if (k0) __syncthreads();
#pragma unroll
        for (int r = 0; r < 4; r++) {
            int i = r * 256 + tid;
            int row = i >> 4, slot = i & 15;
            short8 v = *(const short8*)(A + (size_t)(row0 + row) * K + k0 + slot * 8);
            *(short8*)&A_lds[row][slot * 8] = v;
        }
#pragma unroll
        for (int r = 0; r < 8; r++) {
            int i = r * 256 + tid;
            int col = i >> 4, slot = i & 15;
            short8 v = *(const short8*)(Bt + (size_t)(col0 + col) * K + k0 + slot * 8);
            *(short8*)&B_lds[col][slot * 8] = v;
        }
        __syncthreads();

#pragma unroll
        for (int kk = 0; kk < KC; kk += 32) {
            short8 af[4], bfr[2];
#pragma unroll
            for (int i = 0; i < 4; i++)
                af[i] = *(const short8*)&A_lds[i * 16 + cq][kk + rq * 8];
#pragma unroll
            for (int j = 0; j < 2; j++)
                bfr[j] = *(const short8*)&B_lds[wave * 32 + j * 16 + cq][kk + rq * 8];
#pragma unroll
            for (int i = 0; i < 4; i++)
#pragma unroll
                for (int j = 0; j < 2; j++)
                    acc[i][j] = __builtin_amdgcn_mfma_f32_16x16x32_bf16(af[i], bfr[j], acc[i][j], 0, 0, 0);
        }
    }

    // C write (bf16)
#pragma unroll
    for (int i = 0; i < 4; i++)
#pragma unroll
        for (int j = 0; j < 2; j++) {
            unsigned short* cp = C + (size_t)(row0 + i * 16 + rq * 4) * NCOL + col0 + wave * 32 + j * 16 + cq;
#pragma unroll
            for (int r = 0; r < 4; r++)
                cp[(size_t)r * NCOL] = f2bf(acc[i][j][r]);
        }

    // ---- fused score epilogue ----
    const float* ah = asrc + head * 128;
    const float* dh = adst + head * 128;
    float a0 = ah[wave * 32 + cq], a1 = ah[wave * 32 + 16 + cq];
    float d0 = dh[wave * 32 + cq], d1 = dh[wave * 32 + 16 + cq];

    __syncthreads();  // A_lds no longer needed; reuse as reduction scratch
    float* sred = (float*)&A_lds[0][0];        // [4][64]
    float* dred = sred + 256;                  // [4][64]

#pragma unroll
    for (int i = 0; i < 4; i++)
#pragma unroll
        for (int r = 0; r < 4; r++) {
            float ss = acc[i][0][r] * a0 + acc[i][1][r] * a1;
            float sd = acc[i][0][r] * d0 + acc[i][1][r] * d1;
#pragma unroll
            for (int m = 1; m <= 8; m <<= 1) {
                ss += __shfl_xor(ss, m, 64);
                sd += __shfl_xor(sd, m, 64);
            }
            if (cq == 0) {
                int row = i * 16 + rq * 4 + r;
                sred[wave * 64 + row] = ss;
                dred[wave * 64 + row] = sd;
            }
        }
    __syncthreads();
    if (tid < 64) {
        float ss = sred[tid] + sred[64 + tid] + sred[128 + tid] + sred[192 + tid];
        float sd = dred[tid] + dred[64 + tid] + dred[128 + tid] + dred[192 + tid];
        ssrc[(size_t)(row0 + tid) * SH + head] = ss;
        sdst[(size_t)(row0 + tid) * SH + head] = sd;
    }
}

// ---------------- edge-parallel attention logits (leaky applied) ----------------

__global__ void edge_alpha4_kernel(const int* __restrict__ csr, const int* __restrict__ dstp,
                                   const float4* __restrict__ ssrc4,
                                   const float4* __restrict__ sdst4,
                                   float4* __restrict__ elog4) {
    int p = blockIdx.x * 256 + threadIdx.x;
    if (p >= ETOT) return;
    int s = csr[p], d = dstp[p];
    float4 es = ssrc4[s], ed = sdst4[d];
    float4 e;
    e.x = es.x + ed.x; e.x = e.x > 0.f ? e.x : 0.2f * e.x;
    e.y = es.y + ed.y; e.y = e.y > 0.f ? e.y : 0.2f * e.y;
    e.z = es.z + ed.z; e.z = e.z > 0.f ? e.z : 0.2f * e.z;
    e.w = es.w + ed.w; e.w = e.w > 0.f ? e.w : 0.2f * e.w;
    elog4[p] = e;
}

__global__ void edge_alpha1_kernel(const int* __restrict__ csr, const int* __restrict__ dstp,
                                   const float* __restrict__ ssrc1,
                                   const float* __restrict__ sdst1,
                                   float* __restrict__ elog1) {
    int p = blockIdx.x * 256 + threadIdx.x;
    if (p >= ETOT) return;
    int s = csr[p], d = dstp[p];
    float e = ssrc1[s] + sdst1[d];
    e = e > 0.f ? e : 0.2f * e;
    elog1[p] = e;
}

// ---------------- single-pass softmax + aggregation ----------------
// agg4: one wave per node (4 nodes / 256-thr block). Softmax in registers
// (deg<=64 fast path), gather = contiguous 1 KB row per edge (16 B/lane),
// alpha via shuffle broadcast; head-mean via xor16/32; +bias,ELU,BN -> bf16.

__global__ __launch_bounds__(256) void agg4_kernel(const int* __restrict__ offs,
                                                   const int* __restrict__ csr,
                                                   const unsigned short* __restrict__ hbuf,
                                                   const float4* __restrict__ elog4,
                                                   const float* __restrict__ bias,
                                                   const float* __restrict__ bng,
                                                   const float* __restrict__ bnb,
                                                   const float* __restrict__ bnm,
                                                   const float* __restrict__ bnv,
                                                   unsigned short* __restrict__ outb) {
    int wave = threadIdx.x >> 6, lane = threadIdx.x & 63;
    int d = blockIdx.x * 4 + wave;
    int off = offs[d];
    int deg = offs[d + 1] - off;
    int hh = lane >> 4;
    float acc[8] = {};

    if (deg <= 64) {
        float4 ev; int sreg = 0;
        if (lane < deg) { ev = elog4[off + lane]; sreg = csr[off + lane]; }
        else { ev.x = ev.y = ev.z = ev.w = -1e30f; }
        float4 mx = ev;
#pragma unroll
        for (int m = 32; m >= 1; m >>= 1) {
            mx.x = fmaxf(mx.x, __shfl_xor(mx.x, m, 64));
            mx.y = fmaxf(mx.y, __shfl_xor(mx.y, m, 64));
            mx.z = fmaxf(mx.z, __shfl_xor(mx.z, m, 64));
            mx.w = fmaxf(mx.w, __shfl_xor(mx.w, m, 64));
        }
        float4 p;
        p.x = (lane < deg) ? __expf(ev.x - mx.x) : 0.f;
        p.y = (lane < deg) ? __expf(ev.y - mx.y) : 0.f;
        p.z = (lane < deg) ? __expf(ev.z - mx.z) : 0.f;
        p.w = (lane < deg) ? __expf(ev.w - mx.w) : 0.f;
        float4 z = p;
#pragma unroll
        for (int m = 32; m >= 1; m >>= 1) {
            z.x += __shfl_xor(z.x, m, 64);
            z.y += __shfl_xor(z.y, m, 64);
            z.z += __shfl_xor(z.z, m, 64);
            z.w += __shfl_xor(z.w, m, 64);
        }
        float4 alpha;
        alpha.x = p.x / (z.x + 1e-16f);
        alpha.y = p.y / (z.y + 1e-16f);
        alpha.z = p.z / (z.z + 1e-16f);
        alpha.w = p.w / (z.w + 1e-16f);

        for (int j = 0; j < deg; j++) {
            int s = __shfl(sreg, j, 64);
            float a0 = __shfl(alpha.x, j, 64);
            float a1 = __shfl(alpha.y, j, 64);
            float a2 = __shfl(alpha.z, j, 64);
            float a3 = __shfl(alpha.w, j, 64);
            float a = hh == 0 ? a0 : hh == 1 ? a1 : hh == 2 ? a2 : a3;
            bfx8 hv = *(const bfx8*)(hbuf + (size_t)s * 512 + lane * 8);
#pragma unroll
            for (int i = 0; i < 8; i++) acc[i] += a * bf2f(hv[i]);
        }
    } else {
        float4 mx; mx.x = mx.y = mx.z = mx.w = -1e30f;
        for (int j = lane; j < deg; j += 64) {
            float4 e = elog4[off + j];
            mx.x = fmaxf(mx.x, e.x); mx.y = fmaxf(mx.y, e.y);
            mx.z = fmaxf(mx.z, e.z); mx.w = fmaxf(mx.w, e.w);
        }
#pragma unroll
        for (int m = 32; m >= 1; m >>= 1) {
            mx.x = fmaxf(mx.x, __shfl_xor(mx.x, m, 64));
            mx.y = fmaxf(mx.y, __shfl_xor(mx.y, m, 64));
            mx.z = fmaxf(mx.z, __shfl_xor(mx.z, m, 64));
            mx.w = fmaxf(mx.w, __shfl_xor(mx.w, m, 64));
        }
        float4 z; z.x = z.y = z.z = z.w = 0.f;
        for (int j = lane; j < deg; j += 64) {
            float4 e = elog4[off + j];
            z.x += __expf(e.x - mx.x); z.y += __expf(e.y - mx.y);
            z.z += __expf(e.z - mx.z); z.w += __expf(e.w - mx.w);
        }
#pragma unroll
        for (int m = 32; m >= 1; m >>= 1) {
            z.x += __shfl_xor(z.x, m, 64);
            z.y += __shfl_xor(z.y, m, 64);
            z.z += __shfl_xor(z.z, m, 64);
            z.w += __shfl_xor(z.w, m, 64);
        }
        float4 inv;
        inv.x = 1.f / (z.x + 1e-16f); inv.y = 1.f / (z.y + 1e-16f);
        inv.z = 1.f / (z.z + 1e-16f); inv.w = 1.f / (z.w + 1e-16f);
        float mc = hh == 0 ? mx.x : hh == 1 ? mx.y : hh == 2 ? mx.z : mx.w;
        float ic = hh == 0 ? inv.x : hh == 1 ? inv.y : hh == 2 ? inv.z : inv.w;
        for (int j = 0; j < deg; j++) {
            float4 e = elog4[off + j];
            int s = csr[off + j];
            float ec = hh == 0 ? e.x : hh == 1 ? e.y : hh == 2 ? e.z : e.w;
            float a = __expf(ec - mc) * ic;
            bfx8 hv = *(const bfx8*)(hbuf + (size_t)s * 512 + lane * 8);
#pragma unroll
            for (int i = 0; i < 8; i++) acc[i] += a * bf2f(hv[i]);
        }
    }

    // head-mean: channel group g=(lane&15) lives in lanes g, g+16, g+32, g+48
#pragma unroll
    for (int i = 0; i < 8; i++) {
        acc[i] += __shfl_xor(acc[i], 16, 64);
        acc[i] += __shfl_xor(acc[i], 32, 64);
    }
    if (lane < 16) {
        int c0 = lane * 8;
        bfx8 o;
#pragma unroll
        for (int i = 0; i < 8; i++) {
            int c = c0 + i;
            float v = acc[i] * 0.25f + bias[c];
            v = v > 0.f ? v : (__expf(v) - 1.0f);
            float sc = bng[c] * rsqrtf(bnv[c] + 1e-5f);
            v = (v - bnm[c]) * sc + bnb[c];
            o[i] = f2bf(v);
        }
        *(bfx8*)(outb + (size_t)d * 128 + c0) = o;
    }
}

// agg1: layer-3 (H=1). One wave per node; +bias then atomicAdd into pool.

__global__ __launch_bounds__(256) void agg1_kernel(const int* __restrict__ offs,
                                                   const int* __restrict__ csr,
                                                   const unsigned short* __restrict__ hbuf1,
                                                   const float* __restrict__ elog1,
                                                   const float* __restrict__ bias,
                                                   float* __restrict__ pool,
                                                   const int* __restrict__ batch) {
    int wave = threadIdx.x >> 6, lane = threadIdx.x & 63;
    int d = blockIdx.x * 4 + wave;
    int off = offs[d];
    int deg = offs[d + 1] - off;
    int half = lane >> 5, li = lane & 31;
    float acc[4] = {};

    if (deg <= 64) {
        float ev = -1e30f; int sreg = 0;
        if (lane < deg) { ev = elog1[off + lane]; sreg = csr[off + lane]; }
        float mx = ev;
#pragma unroll
        for (int m = 32; m >= 1; m >>= 1) mx = fmaxf(mx, __shfl_xor(mx, m, 64));
        float p = (lane < deg) ? __expf(ev - mx) : 0.f;
        float z = p;
#pragma unroll
        for (int m = 32; m >= 1; m >>= 1) z += __shfl_xor(z, m, 64);
        float alpha = p / (z + 1e-16f);
        for (int j = half; j < deg; j += 2) {
            int s = __shfl(sreg, j, 64);
            float a = __shfl(alpha, j, 64);
            bfx4 hv = *(const bfx4*)(hbuf1 + (size_t)s * 128 + li * 4);
#pragma unroll
            for (int i = 0; i < 4; i++) acc[i] += a * bf2f(hv[i]);
        }
    } else {
        float mx = -1e30f;
        for (int j = lane; j < deg; j += 64) mx = fmaxf(mx, elog1[off + j]);
#pragma unroll
        for (int m = 32; m >= 1; m >>= 1) mx = fmaxf(mx, __shfl_xor(mx, m, 64));
        float z = 0.f;
        for (int j = lane; j < deg; j += 64) z += __expf(elog1[off + j] - mx);
#pragma unroll
        for (int m = 32; m >= 1; m >>= 1) z += __shfl_xor(z, m, 64);
        float inv = 1.f / (z + 1e-16f);
        for (int j = half; j < deg; j += 2) {
            int s = csr[off + j];
            float a = __expf(elog1[off + j] - mx) * inv;
            bfx4 hv = *(const bfx4*)(hbuf1 + (size_t)s * 128 + li * 4);
#pragma unroll
            for (int i = 0; i < 4; i++) acc[i] += a * bf2f(hv[i]);
        }
    }

#pragma unroll
    for (int i = 0; i < 4; i++) acc[i] += __shfl_xor(acc[i], 32, 64);
    if (lane < 32) {
        int g = batch[d];
#pragma unroll
        for (int i = 0; i < 4; i++)
            atomicAdd(&pool[g * 128 + li * 4 + i], acc[i] + bias[li * 4 + i]);
    }
}

__global__ void final_kernel(const float* __restrict__ pool, const float* __restrict__ cnt,
                             float* __restrict__ out) {
    int i = blockIdx.x * 256 + threadIdx.x;
    if (i >= NG * DHID) return;
    out[i] = pool[i] / fmaxf(cnt[i / DHID], 1.0f);
}

// ---------------- host ----------------

extern "C" void kernel_launch(void* const* d_in, const int* in_sizes, int n_in,
                              void* d_out, int out_size, void* d_ws, size_t ws_size,
                              hipStream_t stream) {
    const float* x    = (const float*)d_in[0];
    const int* src    = (const int*)d_in[1];
    const int* dst    = (const int*)d_in[2];
    const int* batch  = (const int*)d_in[3];
    const float* W1   = (const float*)d_in[4];
    const float* as1  = (const float*)d_in[5];
    const float* ad1  = (const float*)d_in[6];
    const float* b1   = (const float*)d_in[7];
    const float* g1   = (const float*)d_in[8];
    const float* be1  = (const float*)d_in[9];
    const float* m1   = (const float*)d_in[10];
    const float* v1   = (const float*)d_in[11];
    const float* W2   = (const float*)d_in[12];
    const float* as2  = (const float*)d_in[13];
    const float* ad2  = (const float*)d_in[14];
    const float* b2   = (const float*)d_in[15];
    const float* g2   = (const float*)d_in[16];
    const float* be2  = (const float*)d_in[17];
    const float* m2   = (const float*)d_in[18];
    const float* v2   = (const float*)d_in[19];
    const float* W3   = (const float*)d_in[20];
    const float* as3  = (const float*)d_in[21];
    const float* ad3  = (const float*)d_in[22];
    const float* b3   = (const float*)d_in[23];
    float* out = (float*)d_out;

    char* w = (char*)d_ws;
    size_t o = 0;
    auto alloc = [&](size_t bytes) -> void* {
        void* p = w + o;
        o += (bytes + 255) & ~(size_t)255;
        return p;
    };
    int* deg     = (int*)alloc((size_t)N_NODES * 4);
    int* offs    = (int*)alloc((size_t)(N_NODES + 1) * 4);
    int* cursor  = (int*)alloc((size_t)N_NODES * 4);
    int* csr     = (int*)alloc((size_t)ETOT * 4);
    int* dstp    = (int*)alloc((size_t)ETOT * 4);
    float* ssrc  = (float*)alloc((size_t)N_NODES * NHEAD * 4);
    float* sdst  = (float*)alloc((size_t)N_NODES * NHEAD * 4);
    float* elog  = (float*)alloc((size_t)ETOT * NHEAD * 4);
    float* pool  = (float*)alloc((size_t)NG * 128 * 4);
    float* cnt   = (float*)alloc((size_t)NG * 4);
    unsigned short* hbuf = (unsigned short*)alloc((size_t)N_NODES * 512 * 2);
    unsigned short* xb   = (unsigned short*)alloc((size_t)N_NODES * DIN * 2);
    unsigned short* xbuf = (unsigned short*)alloc((size_t)N_NODES * 128 * 2);
    unsigned short* W1t  = (unsigned short*)alloc((size_t)512 * 256 * 2);
    unsigned short* W2t  = (unsigned short*)alloc((size_t)512 * 128 * 2);
    unsigned short* W3t  = (unsigned short*)alloc((size_t)128 * 128 * 2);

    (void)hipMemsetAsync(deg, 0, (size_t)N_NODES * 4, stream);
    (void)hipMemsetAsync(pool, 0, (size_t)NG * 128 * 4, stream);
    (void)hipMemsetAsync(cnt, 0, (size_t)NG * 4, stream);

    // CSR build (+ pool counts)
    count_kernel<<<(ETOT + 255) / 256, 256, 0, stream>>>(dst, deg, batch, cnt);
    scan_kernel<<<1, 1024, 0, stream>>>(deg, offs, cursor);
    fill_kernel<<<(ETOT + 255) / 256, 256, 0, stream>>>(src, dst, cursor, csr, dstp);

    // dtype prep
    cvt_bf16_kernel<<<(N_NODES * DIN + 255) / 256, 256, 0, stream>>>(x, xb, N_NODES * DIN);
    transpose_w_kernel<<<(256 * 512 + 255) / 256, 256, 0, stream>>>(W1, W1t, 256, 512);
    transpose_w_kernel<<<(128 * 512 + 255) / 256, 256, 0, stream>>>(W2, W2t, 128, 512);
    transpose_w_kernel<<<(128 * 128 + 255) / 256, 256, 0, stream>>>(W3, W3t, 128, 128);

    // ----- layer 1 -----
    mfma_gemm_kernel<256, 512><<<dim3(N_NODES / 64, 4), 256, 0, stream>>>(
        xb, W1t, hbuf, as1, ad1, ssrc, sdst);
    edge_alpha4_kernel<<<(ETOT + 255) / 256, 256, 0, stream>>>(
        csr, dstp, (const float4*)ssrc, (const float4*)sdst, (float4*)elog);
    agg4_kernel<<<N_NODES / 4, 256, 0, stream>>>(offs, csr, hbuf, (const float4*)elog,
                                                 b1, g1, be1, m1, v1, xbuf);

    // ----- layer 2 -----
    mfma_gemm_kernel<128, 512><<<dim3(N_NODES / 64, 4), 256, 0, stream>>>(
        xbuf, W2t, hbuf, as2, ad2, ssrc, sdst);
    edge_alpha4_kernel<<<(ETOT + 255) / 256, 256, 0, stream>>>(
        csr, dstp, (const float4*)ssrc, (const float4*)sdst, (float4*)elog);
    agg4_kernel<<<N_NODES / 4, 256, 0, stream>>>(offs, csr, hbuf, (const float4*)elog,
                                                 b2, g2, be2, m2, v2, xbuf);

    // ----- layer 3 -----
    mfma_gemm_kernel<128, 128><<<dim3(N_NODES / 64, 1), 256, 0, stream>>>(
        xbuf, W3t, hbuf, as3, ad3, ssrc, sdst);
    edge_alpha1_kernel<<<(ETOT + 255) / 256, 256, 0, stream>>>(csr, dstp, ssrc, sdst, elog);
    agg1_kernel<<<N_NODES / 4, 256, 0, stream>>>(offs, csr, hbuf, elog, b3, pool, batch);

    final_kernel<<<(NG * 128 + 255) / 256, 256, 0, stream>>>(pool, cnt, out);
}

// Round 6
// 518.455 us; speedup vs baseline: 2.0202x; 1.1944x over previous
//
#include <hip/hip_runtime.h>
#include <cstdint>

#define N_NODES 40000
#define N_EDGES 400000
#define DIN 256
#define DHID 128
#define NG 256
#define NHEAD 4
#define ETOT (N_EDGES + N_NODES)

typedef __attribute__((ext_vector_type(8))) short short8;
typedef __attribute__((ext_vector_type(8))) unsigned short bfx8;
typedef __attribute__((ext_vector_type(4))) unsigned short bfx4;
typedef __attribute__((ext_vector_type(4))) float floatx4;

static __device__ __forceinline__ unsigned short f2bf(float f) {
    unsigned u = __float_as_uint(f);
    unsigned r = (u + 0x7FFFu + ((u >> 16) & 1u)) >> 16;
    return (unsigned short)r;
}
static __device__ __forceinline__ float bf2f(unsigned short s) {
    return __uint_as_float((unsigned)s << 16);
}

// ---------------- CSR construction ----------------

__global__ void count_kernel(const int* __restrict__ dst, int* __restrict__ deg) {
    int i = blockIdx.x * 256 + threadIdx.x;
    if (i >= ETOT) return;
    int d = (i < N_EDGES) ? dst[i] : (i - N_EDGES);
    atomicAdd(&deg[d], 1);
}

__global__ __launch_bounds__(1024) void scan_kernel(const int* __restrict__ deg,
                                                    int* __restrict__ offs,
                                                    int* __restrict__ cursor) {
    const int VPT = 40;
    __shared__ int wsum[16];
    int t = threadIdx.x;
    int lane = t & 63, wv = t >> 6;
    int base = t * VPT;
    int vals[VPT];
    int run = 0;
#pragma unroll
    for (int i = 0; i < VPT; i++) {
        int idx = base + i;
        int v = (idx < N_NODES) ? deg[idx] : 0;
        vals[i] = run;
        run += v;
    }
    int inc = run;
#pragma unroll
    for (int off = 1; off < 64; off <<= 1) {
        int n = __shfl_up(inc, off, 64);
        if (lane >= off) inc += n;
    }
    if (lane == 63) wsum[wv] = inc;
    __syncthreads();
    if (t == 0) {
        int c = 0;
#pragma unroll
        for (int i = 0; i < 16; i++) { int v = wsum[i]; wsum[i] = c; c += v; }
    }
    __syncthreads();
    int excl = wsum[wv] + inc - run;
#pragma unroll
    for (int i = 0; i < VPT; i++) {
        int idx = base + i;
        if (idx < N_NODES) { int o = excl + vals[i]; offs[idx] = o; cursor[idx] = o; }
    }
    if (t == 0) offs[N_NODES] = ETOT;
}

__global__ void fill_kernel(const int* __restrict__ src, const int* __restrict__ dst,
                            int* __restrict__ cursor, int* __restrict__ csr,
                            int* __restrict__ dstp) {
    int i = blockIdx.x * 256 + threadIdx.x;
    if (i >= ETOT) return;
    int s, d;
    if (i < N_EDGES) { s = src[i]; d = dst[i]; } else { s = d = i - N_EDGES; }
    int pos = atomicAdd(&cursor[d], 1);
    csr[pos] = s;
    dstp[pos] = d;
}

// ---------------- dtype prep ----------------

__global__ void cvt_bf16_kernel(const float* __restrict__ in, unsigned short* __restrict__ out,
                                int n) {
    int i = blockIdx.x * 256 + threadIdx.x;
    if (i >= n) return;
    out[i] = f2bf(in[i]);
}

__global__ void transpose_w_kernel(const float* __restrict__ W, unsigned short* __restrict__ Wt,
                                   int K, int Nn) {
    int i = blockIdx.x * 256 + threadIdx.x;
    if (i >= K * Nn) return;
    int k = i / Nn, n = i - k * Nn;
    Wt[(size_t)n * K + k] = f2bf(W[i]);
}

// ---------------- MFMA GEMM + fused attention-score epilogue ----------------

template <int K, int NCOL>
__global__ __launch_bounds__(256) void mfma_gemm_kernel(const unsigned short* __restrict__ A,
                                                        const unsigned short* __restrict__ Bt,
                                                        unsigned short* __restrict__ C,
                                                        const float* __restrict__ asrc,
                                                        const float* __restrict__ adst,
                                                        float* __restrict__ ssrc,
                                                        float* __restrict__ sdst) {
    constexpr int KC = 128;
    constexpr int KP = KC + 8;
    constexpr int SH = NCOL / 128;
    __shared__ alignas(16) unsigned short A_lds[64][KP];
    __shared__ alignas(16) unsigned short B_lds[128][KP];

    const int tid = threadIdx.x;
    const int lane = tid & 63, wave = tid >> 6;
    const int row0 = blockIdx.x * 64;
    const int head = blockIdx.y;
    const int col0 = head * 128;
    const int cq = lane & 15, rq = lane >> 4;

    floatx4 acc[4][2] = {};

    for (int k0 = 0; k0 < K; k0 += KC) {
        if (k0) __syncthreads();
#pragma unroll
        for (int r = 0; r < 4; r++) {
            int i = r * 256 + tid;
            int row = i >> 4, slot = i & 15;
            short8 v = *(const short8*)(A + (size_t)(row0 + row) * K + k0 + slot * 8);
            *(short8*)&A_lds[row][slot * 8] = v;
        }
#pragma unroll
        for (int r = 0; r < 8; r++) {
            int i = r * 256 + tid;
            int col = i >> 4, slot = i & 15;
            short8 v = *(const short8*)(Bt + (size_t)(col0 + col) * K + k0 + slot * 8);
            *(short8*)&B_lds[col][slot * 8] = v;
        }
        __syncthreads();

#pragma unroll
        for (int kk = 0; kk < KC; kk += 32) {
            short8 af[4], bfr[2];
#pragma unroll
            for (int i = 0; i < 4; i++)
                af[i] = *(const short8*)&A_lds[i * 16 + cq][kk + rq * 8];
#pragma unroll
            for (int j = 0; j < 2; j++)
                bfr[j] = *(const short8*)&B_lds[wave * 32 + j * 16 + cq][kk + rq * 8];
#pragma unroll
            for (int i = 0; i < 4; i++)
#pragma unroll
                for (int j = 0; j < 2; j++)
                    acc[i][j] = __builtin_amdgcn_mfma_f32_16x16x32_bf16(af[i], bfr[j], acc[i][j], 0, 0, 0);
        }
    }

    // C write (bf16)
#pragma unroll
    for (int i = 0; i < 4; i++)
#pragma unroll
        for (int j = 0; j < 2; j++) {
            unsigned short* cp = C + (size_t)(row0 + i * 16 + rq * 4) * NCOL + col0 + wave * 32 + j * 16 + cq;
#pragma unroll
            for (int r = 0; r < 4; r++)
                cp[(size_t)r * NCOL] = f2bf(acc[i][j][r]);
        }

    // ---- fused score epilogue ----
    const float* ah = asrc + head * 128;
    const float* dh = adst + head * 128;
    float a0 = ah[wave * 32 + cq], a1 = ah[wave * 32 + 16 + cq];
    float d0 = dh[wave * 32 + cq], d1 = dh[wave * 32 + 16 + cq];

    __syncthreads();
    float* sred = (float*)&A_lds[0][0];        // [4][64]
    float* dred = sred + 256;                  // [4][64]

#pragma unroll
    for (int i = 0; i < 4; i++)
#pragma unroll
        for (int r = 0; r < 4; r++) {
            float ss = acc[i][0][r] * a0 + acc[i][1][r] * a1;
            float sd = acc[i][0][r] * d0 + acc[i][1][r] * d1;
#pragma unroll
            for (int m = 1; m <= 8; m <<= 1) {
                ss += __shfl_xor(ss, m, 64);
                sd += __shfl_xor(sd, m, 64);
            }
            if (cq == 0) {
                int row = i * 16 + rq * 4 + r;
                sred[wave * 64 + row] = ss;
                dred[wave * 64 + row] = sd;
            }
        }
    __syncthreads();
    if (tid < 64) {
        float ss = sred[tid] + sred[64 + tid] + sred[128 + tid] + sred[192 + tid];
        float sd = dred[tid] + dred[64 + tid] + dred[128 + tid] + dred[192 + tid];
        ssrc[(size_t)(row0 + tid) * SH + head] = ss;
        sdst[(size_t)(row0 + tid) * SH + head] = sd;
    }
}

// ---------------- edge-parallel attention logits (leaky applied) ----------------

__global__ void edge_alpha4_kernel(const int* __restrict__ csr, const int* __restrict__ dstp,
                                   const float4* __restrict__ ssrc4,
                                   const float4* __restrict__ sdst4,
                                   float4* __restrict__ elog4) {
    int p = blockIdx.x * 256 + threadIdx.x;
    if (p >= ETOT) return;
    int s = csr[p], d = dstp[p];
    float4 es = ssrc4[s], ed = sdst4[d];
    float4 e;
    e.x = es.x + ed.x; e.x = e.x > 0.f ? e.x : 0.2f * e.x;
    e.y = es.y + ed.y; e.y = e.y > 0.f ? e.y : 0.2f * e.y;
    e.z = es.z + ed.z; e.z = e.z > 0.f ? e.z : 0.2f * e.z;
    e.w = es.w + ed.w; e.w = e.w > 0.f ? e.w : 0.2f * e.w;
    elog4[p] = e;
}

__global__ void edge_alpha1_kernel(const int* __restrict__ csr, const int* __restrict__ dstp,
                                   const float* __restrict__ ssrc1,
                                   const float* __restrict__ sdst1,
                                   float* __restrict__ elog1) {
    int p = blockIdx.x * 256 + threadIdx.x;
    if (p >= ETOT) return;
    int s = csr[p], d = dstp[p];
    float e = ssrc1[s] + sdst1[d];
    e = e > 0.f ? e : 0.2f * e;
    elog1[p] = e;
}

// ---------------- single-pass softmax + aggregation ----------------

__global__ __launch_bounds__(256) void agg4_kernel(const int* __restrict__ offs,
                                                   const int* __restrict__ csr,
                                                   const unsigned short* __restrict__ hbuf,
                                                   const float4* __restrict__ elog4,
                                                   const float* __restrict__ bias,
                                                   const float* __restrict__ bng,
                                                   const float* __restrict__ bnb,
                                                   const float* __restrict__ bnm,
                                                   const float* __restrict__ bnv,
                                                   unsigned short* __restrict__ outb) {
    int wave = threadIdx.x >> 6, lane = threadIdx.x & 63;
    int d = blockIdx.x * 4 + wave;
    int off = offs[d];
    int deg = offs[d + 1] - off;
    int hh = lane >> 4;
    float acc[8] = {};

    if (deg <= 64) {
        float4 ev; int sreg = 0;
        if (lane < deg) { ev = elog4[off + lane]; sreg = csr[off + lane]; }
        else { ev.x = ev.y = ev.z = ev.w = -1e30f; }
        float4 mx = ev;
#pragma unroll
        for (int m = 32; m >= 1; m >>= 1) {
            mx.x = fmaxf(mx.x, __shfl_xor(mx.x, m, 64));
            mx.y = fmaxf(mx.y, __shfl_xor(mx.y, m, 64));
            mx.z = fmaxf(mx.z, __shfl_xor(mx.z, m, 64));
            mx.w = fmaxf(mx.w, __shfl_xor(mx.w, m, 64));
        }
        float4 p;
        p.x = (lane < deg) ? __expf(ev.x - mx.x) : 0.f;
        p.y = (lane < deg) ? __expf(ev.y - mx.y) : 0.f;
        p.z = (lane < deg) ? __expf(ev.z - mx.z) : 0.f;
        p.w = (lane < deg) ? __expf(ev.w - mx.w) : 0.f;
        float4 z = p;
#pragma unroll
        for (int m = 32; m >= 1; m >>= 1) {
            z.x += __shfl_xor(z.x, m, 64);
            z.y += __shfl_xor(z.y, m, 64);
            z.z += __shfl_xor(z.z, m, 64);
            z.w += __shfl_xor(z.w, m, 64);
        }
        float4 alpha;
        alpha.x = p.x / (z.x + 1e-16f);
        alpha.y = p.y / (z.y + 1e-16f);
        alpha.z = p.z / (z.z + 1e-16f);
        alpha.w = p.w / (z.w + 1e-16f);

        for (int j = 0; j < deg; j++) {
            int s = __shfl(sreg, j, 64);
            float a0 = __shfl(alpha.x, j, 64);
            float a1 = __shfl(alpha.y, j, 64);
            float a2 = __shfl(alpha.z, j, 64);
            float a3 = __shfl(alpha.w, j, 64);
            float a = hh == 0 ? a0 : hh == 1 ? a1 : hh == 2 ? a2 : a3;
            bfx8 hv = *(const bfx8*)(hbuf + (size_t)s * 512 + lane * 8);
#pragma unroll
            for (int i = 0; i < 8; i++) acc[i] += a * bf2f(hv[i]);
        }
    } else {
        float4 mx; mx.x = mx.y = mx.z = mx.w = -1e30f;
        for (int j = lane; j < deg; j += 64) {
            float4 e = elog4[off + j];
            mx.x = fmaxf(mx.x, e.x); mx.y = fmaxf(mx.y, e.y);
            mx.z = fmaxf(mx.z, e.z); mx.w = fmaxf(mx.w, e.w);
        }
#pragma unroll
        for (int m = 32; m >= 1; m >>= 1) {
            mx.x = fmaxf(mx.x, __shfl_xor(mx.x, m, 64));
            mx.y = fmaxf(mx.y, __shfl_xor(mx.y, m, 64));
            mx.z = fmaxf(mx.z, __shfl_xor(mx.z, m, 64));
            mx.w = fmaxf(mx.w, __shfl_xor(mx.w, m, 64));
        }
        float4 z; z.x = z.y = z.z = z.w = 0.f;
        for (int j = lane; j < deg; j += 64) {
            float4 e = elog4[off + j];
            z.x += __expf(e.x - mx.x); z.y += __expf(e.y - mx.y);
            z.z += __expf(e.z - mx.z); z.w += __expf(e.w - mx.w);
        }
#pragma unroll
        for (int m = 32; m >= 1; m >>= 1) {
            z.x += __shfl_xor(z.x, m, 64);
            z.y += __shfl_xor(z.y, m, 64);
            z.z += __shfl_xor(z.z, m, 64);
            z.w += __shfl_xor(z.w, m, 64);
        }
        float4 inv;
        inv.x = 1.f / (z.x + 1e-16f); inv.y = 1.f / (z.y + 1e-16f);
        inv.z = 1.f / (z.z + 1e-16f); inv.w = 1.f / (z.w + 1e-16f);
        float mc = hh == 0 ? mx.x : hh == 1 ? mx.y : hh == 2 ? mx.z : mx.w;
        float ic = hh == 0 ? inv.x : hh == 1 ? inv.y : hh == 2 ? inv.z : inv.w;
        for (int j = 0; j < deg; j++) {
            float4 e = elog4[off + j];
            int s = csr[off + j];
            float ec = hh == 0 ? e.x : hh == 1 ? e.y : hh == 2 ? e.z : e.w;
            float a = __expf(ec - mc) * ic;
            bfx8 hv = *(const bfx8*)(hbuf + (size_t)s * 512 + lane * 8);
#pragma unroll
            for (int i = 0; i < 8; i++) acc[i] += a * bf2f(hv[i]);
        }
    }

#pragma unroll
    for (int i = 0; i < 8; i++) {
        acc[i] += __shfl_xor(acc[i], 16, 64);
        acc[i] += __shfl_xor(acc[i], 32, 64);
    }
    if (lane < 16) {
        int c0 = lane * 8;
        bfx8 o;
#pragma unroll
        for (int i = 0; i < 8; i++) {
            int c = c0 + i;
            float v = acc[i] * 0.25f + bias[c];
            v = v > 0.f ? v : (__expf(v) - 1.0f);
            float sc = bng[c] * rsqrtf(bnv[c] + 1e-5f);
            v = (v - bnm[c]) * sc + bnb[c];
            o[i] = f2bf(v);
        }
        *(bfx8*)(outb + (size_t)d * 128 + c0) = o;
    }
}

// agg1: layer-3 (H=1). One wave per node; writes per-node (acc+bias) fp32 — no atomics.

__global__ __launch_bounds__(256) void agg1_kernel(const int* __restrict__ offs,
                                                   const int* __restrict__ csr,
                                                   const unsigned short* __restrict__ hbuf1,
                                                   const float* __restrict__ elog1,
                                                   const float* __restrict__ bias,
                                                   float* __restrict__ h3out) {
    int wave = threadIdx.x >> 6, lane = threadIdx.x & 63;
    int d = blockIdx.x * 4 + wave;
    int off = offs[d];
    int deg = offs[d + 1] - off;
    int half = lane >> 5, li = lane & 31;
    float acc[4] = {};

    if (deg <= 64) {
        float ev = -1e30f; int sreg = 0;
        if (lane < deg) { ev = elog1[off + lane]; sreg = csr[off + lane]; }
        float mx = ev;
#pragma unroll
        for (int m = 32; m >= 1; m >>= 1) mx = fmaxf(mx, __shfl_xor(mx, m, 64));
        float p = (lane < deg) ? __expf(ev - mx) : 0.f;
        float z = p;
#pragma unroll
        for (int m = 32; m >= 1; m >>= 1) z += __shfl_xor(z, m, 64);
        float alpha = p / (z + 1e-16f);
        for (int j = half; j < deg; j += 2) {
            int s = __shfl(sreg, j, 64);
            float a = __shfl(alpha, j, 64);
            bfx4 hv = *(const bfx4*)(hbuf1 + (size_t)s * 128 + li * 4);
#pragma unroll
            for (int i = 0; i < 4; i++) acc[i] += a * bf2f(hv[i]);
        }
    } else {
        float mx = -1e30f;
        for (int j = lane; j < deg; j += 64) mx = fmaxf(mx, elog1[off + j]);
#pragma unroll
        for (int m = 32; m >= 1; m >>= 1) mx = fmaxf(mx, __shfl_xor(mx, m, 64));
        float z = 0.f;
        for (int j = lane; j < deg; j += 64) z += __expf(elog1[off + j] - mx);
#pragma unroll
        for (int m = 32; m >= 1; m >>= 1) z += __shfl_xor(z, m, 64);
        float inv = 1.f / (z + 1e-16f);
        for (int j = half; j < deg; j += 2) {
            int s = csr[off + j];
            float a = __expf(elog1[off + j] - mx) * inv;
            bfx4 hv = *(const bfx4*)(hbuf1 + (size_t)s * 128 + li * 4);
#pragma unroll
            for (int i = 0; i < 4; i++) acc[i] += a * bf2f(hv[i]);
        }
    }

#pragma unroll
    for (int i = 0; i < 4; i++) acc[i] += __shfl_xor(acc[i], 32, 64);
    if (lane < 32) {
        float4 o;
        o.x = acc[0] + bias[li * 4];
        o.y = acc[1] + bias[li * 4 + 1];
        o.z = acc[2] + bias[li * 4 + 2];
        o.w = acc[3] + bias[li * 4 + 3];
        *(float4*)(h3out + (size_t)d * 128 + li * 4) = o;
    }
}

// ---------------- grouped mean-pool (batch is sorted; binary search per group) ----------------

__global__ __launch_bounds__(256) void pool_kernel(const float* __restrict__ h3,
                                                   const int* __restrict__ batch,
                                                   float* __restrict__ out) {
    __shared__ float red[256];
    int g = blockIdx.x;
    int t = threadIdx.x;
    // lo = first i with batch[i] >= g; hi = first i with batch[i] >= g+1
    int lo = 0, n = N_NODES;
    while (n > 0) { int s = n >> 1; if (batch[lo + s] < g) { lo += s + 1; n -= s + 1; } else n = s; }
    int hi = lo; n = N_NODES - lo;
    while (n > 0) { int s = n >> 1; if (batch[hi + s] < g + 1) { hi += s + 1; n -= s + 1; } else n = s; }
    int c = t & 127;
    float acc = 0.f;
    for (int r = lo + (t >> 7); r < hi; r += 2)
        acc += h3[(size_t)r * 128 + c];
    red[t] = acc;
    __syncthreads();
    if (t < 128)
        out[(size_t)g * 128 + t] = (red[t] + red[t + 128]) / fmaxf((float)(hi - lo), 1.0f);
}

// ---------------- host ----------------

extern "C" void kernel_launch(void* const* d_in, const int* in_sizes, int n_in,
                              void* d_out, int out_size, void* d_ws, size_t ws_size,
                              hipStream_t stream) {
    const float* x    = (const float*)d_in[0];
    const int* src    = (const int*)d_in[1];
    const int* dst    = (const int*)d_in[2];
    const int* batch  = (const int*)d_in[3];
    const float* W1   = (const float*)d_in[4];
    const float* as1  = (const float*)d_in[5];
    const float* ad1  = (const float*)d_in[6];
    const float* b1   = (const float*)d_in[7];
    const float* g1   = (const float*)d_in[8];
    const float* be1  = (const float*)d_in[9];
    const float* m1   = (const float*)d_in[10];
    const float* v1   = (const float*)d_in[11];
    const float* W2   = (const float*)d_in[12];
    const float* as2  = (const float*)d_in[13];
    const float* ad2  = (const float*)d_in[14];
    const float* b2   = (const float*)d_in[15];
    const float* g2   = (const float*)d_in[16];
    const float* be2  = (const float*)d_in[17];
    const float* m2   = (const float*)d_in[18];
    const float* v2   = (const float*)d_in[19];
    const float* W3   = (const float*)d_in[20];
    const float* as3  = (const float*)d_in[21];
    const float* ad3  = (const float*)d_in[22];
    const float* b3   = (const float*)d_in[23];
    float* out = (float*)d_out;

    char* w = (char*)d_ws;
    size_t o = 0;
    auto alloc = [&](size_t bytes) -> void* {
        void* p = w + o;
        o += (bytes + 255) & ~(size_t)255;
        return p;
    };
    int* deg     = (int*)alloc((size_t)N_NODES * 4);
    int* offs    = (int*)alloc((size_t)(N_NODES + 1) * 4);
    int* cursor  = (int*)alloc((size_t)N_NODES * 4);
    int* csr     = (int*)alloc((size_t)ETOT * 4);
    int* dstp    = (int*)alloc((size_t)ETOT * 4);
    float* ssrc  = (float*)alloc((size_t)N_NODES * NHEAD * 4);
    float* sdst  = (float*)alloc((size_t)N_NODES * NHEAD * 4);
    float* elog  = (float*)alloc((size_t)ETOT * NHEAD * 4);
    float* h3out = (float*)alloc((size_t)N_NODES * 128 * 4);
    unsigned short* hbuf = (unsigned short*)alloc((size_t)N_NODES * 512 * 2);
    unsigned short* xb   = (unsigned short*)alloc((size_t)N_NODES * DIN * 2);
    unsigned short* xbuf = (unsigned short*)alloc((size_t)N_NODES * 128 * 2);
    unsigned short* W1t  = (unsigned short*)alloc((size_t)512 * 256 * 2);
    unsigned short* W2t  = (unsigned short*)alloc((size_t)512 * 128 * 2);
    unsigned short* W3t  = (unsigned short*)alloc((size_t)128 * 128 * 2);

    (void)hipMemsetAsync(deg, 0, (size_t)N_NODES * 4, stream);

    // CSR build
    count_kernel<<<(ETOT + 255) / 256, 256, 0, stream>>>(dst, deg);
    scan_kernel<<<1, 1024, 0, stream>>>(deg, offs, cursor);
    fill_kernel<<<(ETOT + 255) / 256, 256, 0, stream>>>(src, dst, cursor, csr, dstp);

    // dtype prep
    cvt_bf16_kernel<<<(N_NODES * DIN + 255) / 256, 256, 0, stream>>>(x, xb, N_NODES * DIN);
    transpose_w_kernel<<<(256 * 512 + 255) / 256, 256, 0, stream>>>(W1, W1t, 256, 512);
    transpose_w_kernel<<<(128 * 512 + 255) / 256, 256, 0, stream>>>(W2, W2t, 128, 512);
    transpose_w_kernel<<<(128 * 128 + 255) / 256, 256, 0, stream>>>(W3, W3t, 128, 128);

    // ----- layer 1 -----
    mfma_gemm_kernel<256, 512><<<dim3(N_NODES / 64, 4), 256, 0, stream>>>(
        xb, W1t, hbuf, as1, ad1, ssrc, sdst);
    edge_alpha4_kernel<<<(ETOT + 255) / 256, 256, 0, stream>>>(
        csr, dstp, (const float4*)ssrc, (const float4*)sdst, (float4*)elog);
    agg4_kernel<<<N_NODES / 4, 256, 0, stream>>>(offs, csr, hbuf, (const float4*)elog,
                                                 b1, g1, be1, m1, v1, xbuf);

    // ----- layer 2 -----
    mfma_gemm_kernel<128, 512><<<dim3(N_NODES / 64, 4), 256, 0, stream>>>(
        xbuf, W2t, hbuf, as2, ad2, ssrc, sdst);
    edge_alpha4_kernel<<<(ETOT + 255) / 256, 256, 0, stream>>>(
        csr, dstp, (const float4*)ssrc, (const float4*)sdst, (float4*)elog);
    agg4_kernel<<<N_NODES / 4, 256, 0, stream>>>(offs, csr, hbuf, (const float4*)elog,
                                                 b2, g2, be2, m2, v2, xbuf);

    // ----- layer 3 -----
    mfma_gemm_kernel<128, 128><<<dim3(N_NODES / 64, 1), 256, 0, stream>>>(
        xbuf, W3t, hbuf, as3, ad3, ssrc, sdst);
    edge_alpha1_kernel<<<(ETOT + 255) / 256, 256, 0, stream>>>(csr, dstp, ssrc, sdst, elog);
    agg1_kernel<<<N_NODES / 4, 256, 0, stream>>>(offs, csr, hbuf, elog, b3, h3out);

    // ----- grouped mean pool -----
    pool_kernel<<<NG, 256, 0, stream>>>(h3out, batch, out);
}

// Round 7
// 503.689 us; speedup vs baseline: 2.0794x; 1.0293x over previous
//
#include <hip/hip_runtime.h>
#include <cstdint>

#define N_NODES 40000
#define N_EDGES 400000
#define DIN 256
#define DHID 128
#define NG 256
#define NHEAD 4
#define ETOT (N_EDGES + N_NODES)

typedef __attribute__((ext_vector_type(8))) short short8;
typedef __attribute__((ext_vector_type(8))) unsigned short bfx8;
typedef __attribute__((ext_vector_type(4))) unsigned short bfx4;
typedef __attribute__((ext_vector_type(4))) float floatx4;

static __device__ __forceinline__ unsigned short f2bf(float f) {
    unsigned u = __float_as_uint(f);
    unsigned r = (u + 0x7FFFu + ((u >> 16) & 1u)) >> 16;
    return (unsigned short)r;
}
static __device__ __forceinline__ float bf2f(unsigned short s) {
    return __uint_as_float((unsigned)s << 16);
}

// ---------------- CSR construction ----------------

__global__ void count_kernel(const int* __restrict__ dst, int* __restrict__ deg) {
    int i = blockIdx.x * 256 + threadIdx.x;
    if (i >= ETOT) return;
    int d = (i < N_EDGES) ? dst[i] : (i - N_EDGES);
    atomicAdd(&deg[d], 1);
}

__global__ __launch_bounds__(1024) void scan_kernel(const int* __restrict__ deg,
                                                    int* __restrict__ offs,
                                                    int* __restrict__ cursor) {
    const int VPT = 40;
    __shared__ int wsum[16];
    int t = threadIdx.x;
    int lane = t & 63, wv = t >> 6;
    int base = t * VPT;
    int vals[VPT];
    int run = 0;
#pragma unroll
    for (int i = 0; i < VPT; i++) {
        int idx = base + i;
        int v = (idx < N_NODES) ? deg[idx] : 0;
        vals[i] = run;
        run += v;
    }
    int inc = run;
#pragma unroll
    for (int off = 1; off < 64; off <<= 1) {
        int n = __shfl_up(inc, off, 64);
        if (lane >= off) inc += n;
    }
    if (lane == 63) wsum[wv] = inc;
    __syncthreads();
    if (t == 0) {
        int c = 0;
#pragma unroll
        for (int i = 0; i < 16; i++) { int v = wsum[i]; wsum[i] = c; c += v; }
    }
    __syncthreads();
    int excl = wsum[wv] + inc - run;
#pragma unroll
    for (int i = 0; i < VPT; i++) {
        int idx = base + i;
        if (idx < N_NODES) { int o = excl + vals[i]; offs[idx] = o; cursor[idx] = o; }
    }
    if (t == 0) offs[N_NODES] = ETOT;
}

__global__ void fill_kernel(const int* __restrict__ src, const int* __restrict__ dst,
                            int* __restrict__ cursor, int* __restrict__ csr) {
    int i = blockIdx.x * 256 + threadIdx.x;
    if (i >= ETOT) return;
    int s, d;
    if (i < N_EDGES) { s = src[i]; d = dst[i]; } else { s = d = i - N_EDGES; }
    int pos = atomicAdd(&cursor[d], 1);
    csr[pos] = s;
}

// ---------------- dtype prep ----------------

__global__ void transpose_w_kernel(const float* __restrict__ W, unsigned short* __restrict__ Wt,
                                   int K, int Nn) {
    int i = blockIdx.x * 256 + threadIdx.x;
    if (i >= K * Nn) return;
    int k = i / Nn, n = i - k * Nn;
    Wt[(size_t)n * K + k] = f2bf(W[i]);
}

// ---------------- MFMA GEMM + fused attention-score epilogue ----------------
// A either bf16 (AF32=false) or fp32 (AF32=true, converted during staging).

template <int K, int NCOL, bool AF32>
__global__ __launch_bounds__(256) void mfma_gemm_kernel(const void* __restrict__ Aptr,
                                                        const unsigned short* __restrict__ Bt,
                                                        unsigned short* __restrict__ C,
                                                        const float* __restrict__ asrc,
                                                        const float* __restrict__ adst,
                                                        float* __restrict__ ssrc,
                                                        float* __restrict__ sdst) {
    constexpr int KC = 128;
    constexpr int KP = KC + 8;
    constexpr int SH = NCOL / 128;
    __shared__ alignas(16) unsigned short A_lds[64][KP];
    __shared__ alignas(16) unsigned short B_lds[128][KP];

    const int tid = threadIdx.x;
    const int lane = tid & 63, wave = tid >> 6;
    const int row0 = blockIdx.x * 64;
    const int head = blockIdx.y;
    const int col0 = head * 128;
    const int cq = lane & 15, rq = lane >> 4;

    floatx4 acc[4][2] = {};

    for (int k0 = 0; k0 < K; k0 += KC) {
        if (k0) __syncthreads();
#pragma unroll
        for (int r = 0; r < 4; r++) {
            int i = r * 256 + tid;
            int row = i >> 4, slot = i & 15;
            if constexpr (AF32) {
                const float* ap = (const float*)Aptr + (size_t)(row0 + row) * K + k0 + slot * 8;
                float4 u0 = *(const float4*)ap;
                float4 u1 = *(const float4*)(ap + 4);
                short8 v;
                v[0] = (short)f2bf(u0.x); v[1] = (short)f2bf(u0.y);
                v[2] = (short)f2bf(u0.z); v[3] = (short)f2bf(u0.w);
                v[4] = (short)f2bf(u1.x); v[5] = (short)f2bf(u1.y);
                v[6] = (short)f2bf(u1.z); v[7] = (short)f2bf(u1.w);
                *(short8*)&A_lds[row][slot * 8] = v;
            } else {
                const unsigned short* ap = (const unsigned short*)Aptr + (size_t)(row0 + row) * K + k0 + slot * 8;
                *(short8*)&A_lds[row][slot * 8] = *(const short8*)ap;
            }
        }
#pragma unroll
        for (int r = 0; r < 8; r++) {
            int i = r * 256 + tid;
            int col = i >> 4, slot = i & 15;
            short8 v = *(const short8*)(Bt + (size_t)(col0 + col) * K + k0 + slot * 8);
            *(short8*)&B_lds[col][slot * 8] = v;
        }
        __syncthreads();

#pragma unroll
        for (int kk = 0; kk < KC; kk += 32) {
            short8 af[4], bfr[2];
#pragma unroll
            for (int i = 0; i < 4; i++)
                af[i] = *(const short8*)&A_lds[i * 16 + cq][kk + rq * 8];
#pragma unroll
            for (int j = 0; j < 2; j++)
                bfr[j] = *(const short8*)&B_lds[wave * 32 + j * 16 + cq][kk + rq * 8];
#pragma unroll
            for (int i = 0; i < 4; i++)
#pragma unroll
                for (int j = 0; j < 2; j++)
                    acc[i][j] = __builtin_amdgcn_mfma_f32_16x16x32_bf16(af[i], bfr[j], acc[i][j], 0, 0, 0);
        }
    }

    // C write (bf16)
#pragma unroll
    for (int i = 0; i < 4; i++)
#pragma unroll
        for (int j = 0; j < 2; j++) {
            unsigned short* cp = C + (size_t)(row0 + i * 16 + rq * 4) * NCOL + col0 + wave * 32 + j * 16 + cq;
#pragma unroll
            for (int r = 0; r < 4; r++)
                cp[(size_t)r * NCOL] = f2bf(acc[i][j][r]);
        }

    // ---- fused score epilogue ----
    const float* ah = asrc + head * 128;
    const float* dh = adst + head * 128;
    float a0 = ah[wave * 32 + cq], a1 = ah[wave * 32 + 16 + cq];
    float d0 = dh[wave * 32 + cq], d1 = dh[wave * 32 + 16 + cq];

    __syncthreads();
    float* sred = (float*)&A_lds[0][0];        // [4][64]
    float* dred = sred + 256;                  // [4][64]

#pragma unroll
    for (int i = 0; i < 4; i++)
#pragma unroll
        for (int r = 0; r < 4; r++) {
            float ss = acc[i][0][r] * a0 + acc[i][1][r] * a1;
            float sd = acc[i][0][r] * d0 + acc[i][1][r] * d1;
#pragma unroll
            for (int m = 1; m <= 8; m <<= 1) {
                ss += __shfl_xor(ss, m, 64);
                sd += __shfl_xor(sd, m, 64);
            }
            if (cq == 0) {
                int row = i * 16 + rq * 4 + r;
                sred[wave * 64 + row] = ss;
                dred[wave * 64 + row] = sd;
            }
        }
    __syncthreads();
    if (tid < 64) {
        float ss = sred[tid] + sred[64 + tid] + sred[128 + tid] + sred[192 + tid];
        float sd = dred[tid] + dred[64 + tid] + dred[128 + tid] + dred[192 + tid];
        ssrc[(size_t)(row0 + tid) * SH + head] = ss;
        sdst[(size_t)(row0 + tid) * SH + head] = sd;
    }
}

// ---------------- fused softmax + aggregation, layer 1/2 (H=4) ----------------
// 256 thr = 4 waves = 2 nodes (2 waves per node: even/odd edges).
// Logits computed inline from ssrc4 (L2-resident). Softmax in registers
// (deg<=64 fast path); alpha + src ids stashed in per-wave LDS for
// broadcast reads; gather unrolled 4-wide for MLP. Head-mean + bias + ELU
// + BN epilogue; cross-wave combine via LDS.

__global__ __launch_bounds__(256) void agg4_kernel(const int* __restrict__ offs,
                                                   const int* __restrict__ csr,
                                                   const unsigned short* __restrict__ hbuf,
                                                   const float4* __restrict__ ssrc4,
                                                   const float4* __restrict__ sdst4,
                                                   const float* __restrict__ bias,
                                                   const float* __restrict__ bng,
                                                   const float* __restrict__ bnb,
                                                   const float* __restrict__ bnm,
                                                   const float* __restrict__ bnv,
                                                   unsigned short* __restrict__ outb) {
    __shared__ alignas(16) float aload[4][64][4];
    __shared__ int sload[4][64];
    __shared__ float red[2][128];

    int wave = threadIdx.x >> 6, lane = threadIdx.x & 63;
    int nodeb = wave >> 1, w2 = wave & 1;
    int d = blockIdx.x * 2 + nodeb;
    int off = offs[d];
    int deg = offs[d + 1] - off;
    int hh = lane >> 4;
    float4 sdv = sdst4[d];
    float acc[8] = {};

    if (deg <= 64) {
        int sreg = 0;
        float4 ev;
        if (lane < deg) {
            sreg = csr[off + lane];
            float4 es = ssrc4[sreg];
            ev.x = es.x + sdv.x; ev.x = ev.x > 0.f ? ev.x : 0.2f * ev.x;
            ev.y = es.y + sdv.y; ev.y = ev.y > 0.f ? ev.y : 0.2f * ev.y;
            ev.z = es.z + sdv.z; ev.z = ev.z > 0.f ? ev.z : 0.2f * ev.z;
            ev.w = es.w + sdv.w; ev.w = ev.w > 0.f ? ev.w : 0.2f * ev.w;
        } else { ev.x = ev.y = ev.z = ev.w = -1e30f; }
        float4 mx = ev;
#pragma unroll
        for (int m = 32; m >= 1; m >>= 1) {
            mx.x = fmaxf(mx.x, __shfl_xor(mx.x, m, 64));
            mx.y = fmaxf(mx.y, __shfl_xor(mx.y, m, 64));
            mx.z = fmaxf(mx.z, __shfl_xor(mx.z, m, 64));
            mx.w = fmaxf(mx.w, __shfl_xor(mx.w, m, 64));
        }
        float4 p;
        p.x = (lane < deg) ? __expf(ev.x - mx.x) : 0.f;
        p.y = (lane < deg) ? __expf(ev.y - mx.y) : 0.f;
        p.z = (lane < deg) ? __expf(ev.z - mx.z) : 0.f;
        p.w = (lane < deg) ? __expf(ev.w - mx.w) : 0.f;
        float4 z = p;
#pragma unroll
        for (int m = 32; m >= 1; m >>= 1) {
            z.x += __shfl_xor(z.x, m, 64);
            z.y += __shfl_xor(z.y, m, 64);
            z.z += __shfl_xor(z.z, m, 64);
            z.w += __shfl_xor(z.w, m, 64);
        }
        float4 alpha;
        alpha.x = p.x / (z.x + 1e-16f);
        alpha.y = p.y / (z.y + 1e-16f);
        alpha.z = p.z / (z.z + 1e-16f);
        alpha.w = p.w / (z.w + 1e-16f);

        *(float4*)&aload[wave][lane][0] = alpha;
        sload[wave][lane] = sreg;

        int j = w2;
        for (; j + 6 < deg; j += 8) {
            int s0 = sload[wave][j],     s1 = sload[wave][j + 2];
            int s2 = sload[wave][j + 4], s3 = sload[wave][j + 6];
            float a0 = aload[wave][j][hh],     a1 = aload[wave][j + 2][hh];
            float a2 = aload[wave][j + 4][hh], a3 = aload[wave][j + 6][hh];
            bfx8 v0 = *(const bfx8*)(hbuf + (size_t)s0 * 512 + lane * 8);
            bfx8 v1 = *(const bfx8*)(hbuf + (size_t)s1 * 512 + lane * 8);
            bfx8 v2 = *(const bfx8*)(hbuf + (size_t)s2 * 512 + lane * 8);
            bfx8 v3 = *(const bfx8*)(hbuf + (size_t)s3 * 512 + lane * 8);
#pragma unroll
            for (int i = 0; i < 8; i++)
                acc[i] += a0 * bf2f(v0[i]) + a1 * bf2f(v1[i]) +
                          a2 * bf2f(v2[i]) + a3 * bf2f(v3[i]);
        }
        for (; j < deg; j += 2) {
            int s = sload[wave][j];
            float a = aload[wave][j][hh];
            bfx8 hv = *(const bfx8*)(hbuf + (size_t)s * 512 + lane * 8);
#pragma unroll
            for (int i = 0; i < 8; i++) acc[i] += a * bf2f(hv[i]);
        }
    } else {
        // generic fallback (rare): redundant softmax per wave, inline logits
        float4 mx; mx.x = mx.y = mx.z = mx.w = -1e30f;
        for (int j = lane; j < deg; j += 64) {
            int s = csr[off + j];
            float4 es = ssrc4[s];
            float4 e;
            e.x = es.x + sdv.x; e.x = e.x > 0.f ? e.x : 0.2f * e.x;
            e.y = es.y + sdv.y; e.y = e.y > 0.f ? e.y : 0.2f * e.y;
            e.z = es.z + sdv.z; e.z = e.z > 0.f ? e.z : 0.2f * e.z;
            e.w = es.w + sdv.w; e.w = e.w > 0.f ? e.w : 0.2f * e.w;
            mx.x = fmaxf(mx.x, e.x); mx.y = fmaxf(mx.y, e.y);
            mx.z = fmaxf(mx.z, e.z); mx.w = fmaxf(mx.w, e.w);
        }
#pragma unroll
        for (int m = 32; m >= 1; m >>= 1) {
            mx.x = fmaxf(mx.x, __shfl_xor(mx.x, m, 64));
            mx.y = fmaxf(mx.y, __shfl_xor(mx.y, m, 64));
            mx.z = fmaxf(mx.z, __shfl_xor(mx.z, m, 64));
            mx.w = fmaxf(mx.w, __shfl_xor(mx.w, m, 64));
        }
        float4 z; z.x = z.y = z.z = z.w = 0.f;
        for (int j = lane; j < deg; j += 64) {
            int s = csr[off + j];
            float4 es = ssrc4[s];
            float4 e;
            e.x = es.x + sdv.x; e.x = e.x > 0.f ? e.x : 0.2f * e.x;
            e.y = es.y + sdv.y; e.y = e.y > 0.f ? e.y : 0.2f * e.y;
            e.z = es.z + sdv.z; e.z = e.z > 0.f ? e.z : 0.2f * e.z;
            e.w = es.w + sdv.w; e.w = e.w > 0.f ? e.w : 0.2f * e.w;
            z.x += __expf(e.x - mx.x); z.y += __expf(e.y - mx.y);
            z.z += __expf(e.z - mx.z); z.w += __expf(e.w - mx.w);
        }
#pragma unroll
        for (int m = 32; m >= 1; m >>= 1) {
            z.x += __shfl_xor(z.x, m, 64);
            z.y += __shfl_xor(z.y, m, 64);
            z.z += __shfl_xor(z.z, m, 64);
            z.w += __shfl_xor(z.w, m, 64);
        }
        float mc = hh == 0 ? mx.x : hh == 1 ? mx.y : hh == 2 ? mx.z : mx.w;
        float zc = hh == 0 ? z.x : hh == 1 ? z.y : hh == 2 ? z.z : z.w;
        float ic = 1.f / (zc + 1e-16f);
        float sdc = hh == 0 ? sdv.x : hh == 1 ? sdv.y : hh == 2 ? sdv.z : sdv.w;
        for (int j = w2; j < deg; j += 2) {
            int s = csr[off + j];
            float4 es = ssrc4[s];
            float ec = hh == 0 ? es.x : hh == 1 ? es.y : hh == 2 ? es.z : es.w;
            ec += sdc; ec = ec > 0.f ? ec : 0.2f * ec;
            float a = __expf(ec - mc) * ic;
            bfx8 hv = *(const bfx8*)(hbuf + (size_t)s * 512 + lane * 8);
#pragma unroll
            for (int i = 0; i < 8; i++) acc[i] += a * bf2f(hv[i]);
        }
    }

    // head-mean partial within wave: channel g=(lane&15) over lanes g,g+16,g+32,g+48
#pragma unroll
    for (int i = 0; i < 8; i++) {
        acc[i] += __shfl_xor(acc[i], 16, 64);
        acc[i] += __shfl_xor(acc[i], 32, 64);
    }
    if (w2 == 0 && lane < 16) {
#pragma unroll
        for (int i = 0; i < 8; i++) red[nodeb][lane * 8 + i] = acc[i];
    }
    __syncthreads();
    if (w2 == 1 && lane < 16) {
        int c0 = lane * 8;
        bfx8 o;
#pragma unroll
        for (int i = 0; i < 8; i++) {
            int c = c0 + i;
            float v = (red[nodeb][c] + acc[i]) * 0.25f + bias[c];
            v = v > 0.f ? v : (__expf(v) - 1.0f);
            float sc = bng[c] * rsqrtf(bnv[c] + 1e-5f);
            v = (v - bnm[c]) * sc + bnb[c];
            o[i] = f2bf(v);
        }
        *(bfx8*)(outb + (size_t)d * 128 + c0) = o;
    }
}

// ---------------- fused softmax + aggregation, layer 3 (H=1) ----------------
// 256 thr = 4 waves = 4 nodes. Inline logits; alpha/src via LDS; half-wave
// edge split with unroll-2; writes dense fp32 h3out (no atomics).

__global__ __launch_bounds__(256) void agg1_kernel(const int* __restrict__ offs,
                                                   const int* __restrict__ csr,
                                                   const unsigned short* __restrict__ hbuf1,
                                                   const float* __restrict__ ssrc1,
                                                   const float* __restrict__ sdst1,
                                                   const float* __restrict__ bias,
                                                   float* __restrict__ h3out) {
    __shared__ float aload[4][64];
    __shared__ int sload[4][64];
    int wave = threadIdx.x >> 6, lane = threadIdx.x & 63;
    int d = blockIdx.x * 4 + wave;
    int off = offs[d];
    int deg = offs[d + 1] - off;
    int half = lane >> 5, li = lane & 31;
    float sdv = sdst1[d];
    float acc[4] = {};

    if (deg <= 64) {
        float ev = -1e30f; int sreg = 0;
        if (lane < deg) {
            sreg = csr[off + lane];
            ev = ssrc1[sreg] + sdv;
            ev = ev > 0.f ? ev : 0.2f * ev;
        }
        float mx = ev;
#pragma unroll
        for (int m = 32; m >= 1; m >>= 1) mx = fmaxf(mx, __shfl_xor(mx, m, 64));
        float p = (lane < deg) ? __expf(ev - mx) : 0.f;
        float z = p;
#pragma unroll
        for (int m = 32; m >= 1; m >>= 1) z += __shfl_xor(z, m, 64);
        aload[wave][lane] = p / (z + 1e-16f);
        sload[wave][lane] = sreg;

        int j = half;
        for (; j + 2 < deg; j += 4) {
            int s0 = sload[wave][j], s1 = sload[wave][j + 2];
            float a0 = aload[wave][j], a1 = aload[wave][j + 2];
            bfx4 v0 = *(const bfx4*)(hbuf1 + (size_t)s0 * 128 + li * 4);
            bfx4 v1 = *(const bfx4*)(hbuf1 + (size_t)s1 * 128 + li * 4);
#pragma unroll
            for (int i = 0; i < 4; i++)
                acc[i] += a0 * bf2f(v0[i]) + a1 * bf2f(v1[i]);
        }
        for (; j < deg; j += 2) {
            int s = sload[wave][j];
            float a = aload[wave][j];
            bfx4 hv = *(const bfx4*)(hbuf1 + (size_t)s * 128 + li * 4);
#pragma unroll
            for (int i = 0; i < 4; i++) acc[i] += a * bf2f(hv[i]);
        }
    } else {
        float mx = -1e30f;
        for (int j = lane; j < deg; j += 64) {
            float e = ssrc1[csr[off + j]] + sdv;
            e = e > 0.f ? e : 0.2f * e;
            mx = fmaxf(mx, e);
        }
#pragma unroll
        for (int m = 32; m >= 1; m >>= 1) mx = fmaxf(mx, __shfl_xor(mx, m, 64));
        float z = 0.f;
        for (int j = lane; j < deg; j += 64) {
            float e = ssrc1[csr[off + j]] + sdv;
            e = e > 0.f ? e : 0.2f * e;
            z += __expf(e - mx);
        }
#pragma unroll
        for (int m = 32; m >= 1; m >>= 1) z += __shfl_xor(z, m, 64);
        float inv = 1.f / (z + 1e-16f);
        for (int j = half; j < deg; j += 2) {
            int s = csr[off + j];
            float e = ssrc1[s] + sdv;
            e = e > 0.f ? e : 0.2f * e;
            float a = __expf(e - mx) * inv;
            bfx4 hv = *(const bfx4*)(hbuf1 + (size_t)s * 128 + li * 4);
#pragma unroll
            for (int i = 0; i < 4; i++) acc[i] += a * bf2f(hv[i]);
        }
    }

#pragma unroll
    for (int i = 0; i < 4; i++) acc[i] += __shfl_xor(acc[i], 32, 64);
    if (lane < 32) {
        float4 o;
        o.x = acc[0] + bias[li * 4];
        o.y = acc[1] + bias[li * 4 + 1];
        o.z = acc[2] + bias[li * 4 + 2];
        o.w = acc[3] + bias[li * 4 + 3];
        *(float4*)(h3out + (size_t)d * 128 + li * 4) = o;
    }
}

// ---------------- grouped mean-pool (batch sorted; binary search) ----------------

__global__ __launch_bounds__(256) void pool_kernel(const float* __restrict__ h3,
                                                   const int* __restrict__ batch,
                                                   float* __restrict__ out) {
    __shared__ float red[256];
    int g = blockIdx.x;
    int t = threadIdx.x;
    int lo = 0, n = N_NODES;
    while (n > 0) { int s = n >> 1; if (batch[lo + s] < g) { lo += s + 1; n -= s + 1; } else n = s; }
    int hi = lo; n = N_NODES - lo;
    while (n > 0) { int s = n >> 1; if (batch[hi + s] < g + 1) { hi += s + 1; n -= s + 1; } else n = s; }
    int c = t & 127;
    float acc = 0.f;
    for (int r = lo + (t >> 7); r < hi; r += 2)
        acc += h3[(size_t)r * 128 + c];
    red[t] = acc;
    __syncthreads();
    if (t < 128)
        out[(size_t)g * 128 + t] = (red[t] + red[t + 128]) / fmaxf((float)(hi - lo), 1.0f);
}

// ---------------- host ----------------

extern "C" void kernel_launch(void* const* d_in, const int* in_sizes, int n_in,
                              void* d_out, int out_size, void* d_ws, size_t ws_size,
                              hipStream_t stream) {
    const float* x    = (const float*)d_in[0];
    const int* src    = (const int*)d_in[1];
    const int* dst    = (const int*)d_in[2];
    const int* batch  = (const int*)d_in[3];
    const float* W1   = (const float*)d_in[4];
    const float* as1  = (const float*)d_in[5];
    const float* ad1  = (const float*)d_in[6];
    const float* b1   = (const float*)d_in[7];
    const float* g1   = (const float*)d_in[8];
    const float* be1  = (const float*)d_in[9];
    const float* m1   = (const float*)d_in[10];
    const float* v1   = (const float*)d_in[11];
    const float* W2   = (const float*)d_in[12];
    const float* as2  = (const float*)d_in[13];
    const float* ad2  = (const float*)d_in[14];
    const float* b2   = (const float*)d_in[15];
    const float* g2   = (const float*)d_in[16];
    const float* be2  = (const float*)d_in[17];
    const float* m2   = (const float*)d_in[18];
    const float* v2   = (const float*)d_in[19];
    const float* W3   = (const float*)d_in[20];
    const float* as3  = (const float*)d_in[21];
    const float* ad3  = (const float*)d_in[22];
    const float* b3   = (const float*)d_in[23];
    float* out = (float*)d_out;

    char* w = (char*)d_ws;
    size_t o = 0;
    auto alloc = [&](size_t bytes) -> void* {
        void* p = w + o;
        o += (bytes + 255) & ~(size_t)255;
        return p;
    };
    int* deg     = (int*)alloc((size_t)N_NODES * 4);
    int* offs    = (int*)alloc((size_t)(N_NODES + 1) * 4);
    int* cursor  = (int*)alloc((size_t)N_NODES * 4);
    int* csr     = (int*)alloc((size_t)ETOT * 4);
    float* ssrc  = (float*)alloc((size_t)N_NODES * NHEAD * 4);
    float* sdst  = (float*)alloc((size_t)N_NODES * NHEAD * 4);
    float* h3out = (float*)alloc((size_t)N_NODES * 128 * 4);
    unsigned short* hbuf = (unsigned short*)alloc((size_t)N_NODES * 512 * 2);
    unsigned short* xbuf = (unsigned short*)alloc((size_t)N_NODES * 128 * 2);
    unsigned short* W1t  = (unsigned short*)alloc((size_t)512 * 256 * 2);
    unsigned short* W2t  = (unsigned short*)alloc((size_t)512 * 128 * 2);
    unsigned short* W3t  = (unsigned short*)alloc((size_t)128 * 128 * 2);

    (void)hipMemsetAsync(deg, 0, (size_t)N_NODES * 4, stream);

    // CSR build
    count_kernel<<<(ETOT + 255) / 256, 256, 0, stream>>>(dst, deg);
    scan_kernel<<<1, 1024, 0, stream>>>(deg, offs, cursor);
    fill_kernel<<<(ETOT + 255) / 256, 256, 0, stream>>>(src, dst, cursor, csr);

    // weight prep
    transpose_w_kernel<<<(256 * 512 + 255) / 256, 256, 0, stream>>>(W1, W1t, 256, 512);
    transpose_w_kernel<<<(128 * 512 + 255) / 256, 256, 0, stream>>>(W2, W2t, 128, 512);
    transpose_w_kernel<<<(128 * 128 + 255) / 256, 256, 0, stream>>>(W3, W3t, 128, 128);

    // ----- layer 1 -----
    mfma_gemm_kernel<256, 512, true><<<dim3(N_NODES / 64, 4), 256, 0, stream>>>(
        x, W1t, hbuf, as1, ad1, ssrc, sdst);
    agg4_kernel<<<N_NODES / 2, 256, 0, stream>>>(offs, csr, hbuf, (const float4*)ssrc,
                                                 (const float4*)sdst, b1, g1, be1, m1, v1, xbuf);

    // ----- layer 2 -----
    mfma_gemm_kernel<128, 512, false><<<dim3(N_NODES / 64, 4), 256, 0, stream>>>(
        xbuf, W2t, hbuf, as2, ad2, ssrc, sdst);
    agg4_kernel<<<N_NODES / 2, 256, 0, stream>>>(offs, csr, hbuf, (const float4*)ssrc,
                                                 (const float4*)sdst, b2, g2, be2, m2, v2, xbuf);

    // ----- layer 3 -----
    mfma_gemm_kernel<128, 128, false><<<dim3(N_NODES / 64, 1), 256, 0, stream>>>(
        xbuf, W3t, hbuf, as3, ad3, ssrc, sdst);
    agg1_kernel<<<N_NODES / 4, 256, 0, stream>>>(offs, csr, hbuf, ssrc, sdst, b3, h3out);

    // ----- grouped mean pool -----
    pool_kernel<<<NG, 256, 0, stream>>>(h3out, batch, out);
}

// Round 8
// 486.054 us; speedup vs baseline: 2.1549x; 1.0363x over previous
//
#include <hip/hip_runtime.h>
#include <cstdint>

#define N_NODES 40000
#define N_EDGES 400000
#define DIN 256
#define DHID 128
#define NG 256
#define NHEAD 4
#define ETOT (N_EDGES + N_NODES)

typedef __attribute__((ext_vector_type(8))) short short8;
typedef __attribute__((ext_vector_type(8))) unsigned short bfx8;
typedef __attribute__((ext_vector_type(4))) unsigned short bfx4;
typedef __attribute__((ext_vector_type(4))) float floatx4;

static __device__ __forceinline__ unsigned short f2bf(float f) {
    unsigned u = __float_as_uint(f);
    unsigned r = (u + 0x7FFFu + ((u >> 16) & 1u)) >> 16;
    return (unsigned short)r;
}
static __device__ __forceinline__ float bf2f(unsigned short s) {
    return __uint_as_float((unsigned)s << 16);
}

// ---------------- CSR construction ----------------

__global__ void count_kernel(const int* __restrict__ dst, int* __restrict__ deg) {
    int i = blockIdx.x * 256 + threadIdx.x;
    if (i >= ETOT) return;
    int d = (i < N_EDGES) ? dst[i] : (i - N_EDGES);
    atomicAdd(&deg[d], 1);
}

__global__ __launch_bounds__(1024) void scan_kernel(const int* __restrict__ deg,
                                                    int* __restrict__ offs,
                                                    int* __restrict__ cursor) {
    const int VPT = 40;
    __shared__ int wsum[16];
    int t = threadIdx.x;
    int lane = t & 63, wv = t >> 6;
    int base = t * VPT;
    int vals[VPT];
    int run = 0;
#pragma unroll
    for (int i = 0; i < VPT; i++) {
        int idx = base + i;
        int v = (idx < N_NODES) ? deg[idx] : 0;
        vals[i] = run;
        run += v;
    }
    int inc = run;
#pragma unroll
    for (int off = 1; off < 64; off <<= 1) {
        int n = __shfl_up(inc, off, 64);
        if (lane >= off) inc += n;
    }
    if (lane == 63) wsum[wv] = inc;
    __syncthreads();
    if (t == 0) {
        int c = 0;
#pragma unroll
        for (int i = 0; i < 16; i++) { int v = wsum[i]; wsum[i] = c; c += v; }
    }
    __syncthreads();
    int excl = wsum[wv] + inc - run;
#pragma unroll
    for (int i = 0; i < VPT; i++) {
        int idx = base + i;
        if (idx < N_NODES) { int o = excl + vals[i]; offs[idx] = o; cursor[idx] = o; }
    }
    if (t == 0) offs[N_NODES] = ETOT;
}

__global__ void fill_kernel(const int* __restrict__ src, const int* __restrict__ dst,
                            int* __restrict__ cursor, int* __restrict__ csr) {
    int i = blockIdx.x * 256 + threadIdx.x;
    if (i >= ETOT) return;
    int s, d;
    if (i < N_EDGES) { s = src[i]; d = dst[i]; } else { s = d = i - N_EDGES; }
    int pos = atomicAdd(&cursor[d], 1);
    csr[pos] = s;
}

// ---------------- dtype prep ----------------

__global__ void transpose_w_kernel(const float* __restrict__ W, unsigned short* __restrict__ Wt,
                                   int K, int Nn) {
    int i = blockIdx.x * 256 + threadIdx.x;
    if (i >= K * Nn) return;
    int k = i / Nn, n = i - k * Nn;
    Wt[(size_t)n * K + k] = f2bf(W[i]);
}

// ---------------- MFMA GEMM + fused attention-score epilogue ----------------

template <int K, int NCOL, bool AF32>
__global__ __launch_bounds__(256) void mfma_gemm_kernel(const void* __restrict__ Aptr,
                                                        const unsigned short* __restrict__ Bt,
                                                        unsigned short* __restrict__ C,
                                                        const float* __restrict__ asrc,
                                                        const float* __restrict__ adst,
                                                        float* __restrict__ ssrc,
                                                        float* __restrict__ sdst) {
    constexpr int KC = 128;
    constexpr int KP = KC + 8;
    constexpr int SH = NCOL / 128;
    __shared__ alignas(16) unsigned short A_lds[64][KP];
    __shared__ alignas(16) unsigned short B_lds[128][KP];

    const int tid = threadIdx.x;
    const int lane = tid & 63, wave = tid >> 6;
    const int row0 = blockIdx.x * 64;
    const int head = blockIdx.y;
    const int col0 = head * 128;
    const int cq = lane & 15, rq = lane >> 4;

    floatx4 acc[4][2] = {};

    for (int k0 = 0; k0 < K; k0 += KC) {
        if (k0) __syncthreads();
#pragma unroll
        for (int r = 0; r < 4; r++) {
            int i = r * 256 + tid;
            int row = i >> 4, slot = i & 15;
            if constexpr (AF32) {
                const float* ap = (const float*)Aptr + (size_t)(row0 + row) * K + k0 + slot * 8;
                float4 u0 = *(const float4*)ap;
                float4 u1 = *(const float4*)(ap + 4);
                short8 v;
                v[0] = (short)f2bf(u0.x); v[1] = (short)f2bf(u0.y);
                v[2] = (short)f2bf(u0.z); v[3] = (short)f2bf(u0.w);
                v[4] = (short)f2bf(u1.x); v[5] = (short)f2bf(u1.y);
                v[6] = (short)f2bf(u1.z); v[7] = (short)f2bf(u1.w);
                *(short8*)&A_lds[row][slot * 8] = v;
            } else {
                const unsigned short* ap = (const unsigned short*)Aptr + (size_t)(row0 + row) * K + k0 + slot * 8;
                *(short8*)&A_lds[row][slot * 8] = *(const short8*)ap;
            }
        }
#pragma unroll
        for (int r = 0; r < 8; r++) {
            int i = r * 256 + tid;
            int col = i >> 4, slot = i & 15;
            short8 v = *(const short8*)(Bt + (size_t)(col0 + col) * K + k0 + slot * 8);
            *(short8*)&B_lds[col][slot * 8] = v;
        }
        __syncthreads();

#pragma unroll
        for (int kk = 0; kk < KC; kk += 32) {
            short8 af[4], bfr[2];
#pragma unroll
            for (int i = 0; i < 4; i++)
                af[i] = *(const short8*)&A_lds[i * 16 + cq][kk + rq * 8];
#pragma unroll
            for (int j = 0; j < 2; j++)
                bfr[j] = *(const short8*)&B_lds[wave * 32 + j * 16 + cq][kk + rq * 8];
#pragma unroll
            for (int i = 0; i < 4; i++)
#pragma unroll
                for (int j = 0; j < 2; j++)
                    acc[i][j] = __builtin_amdgcn_mfma_f32_16x16x32_bf16(af[i], bfr[j], acc[i][j], 0, 0, 0);
        }
    }

    // C write (bf16)
#pragma unroll
    for (int i = 0; i < 4; i++)
#pragma unroll
        for (int j = 0; j < 2; j++) {
            unsigned short* cp = C + (size_t)(row0 + i * 16 + rq * 4) * NCOL + col0 + wave * 32 + j * 16 + cq;
#pragma unroll
            for (int r = 0; r < 4; r++)
                cp[(size_t)r * NCOL] = f2bf(acc[i][j][r]);
        }

    // ---- fused score epilogue ----
    const float* ah = asrc + head * 128;
    const float* dh = adst + head * 128;
    float a0 = ah[wave * 32 + cq], a1 = ah[wave * 32 + 16 + cq];
    float d0 = dh[wave * 32 + cq], d1 = dh[wave * 32 + 16 + cq];

    __syncthreads();
    float* sred = (float*)&A_lds[0][0];        // [4][64]
    float* dred = sred + 256;                  // [4][64]

#pragma unroll
    for (int i = 0; i < 4; i++)
#pragma unroll
        for (int r = 0; r < 4; r++) {
            float ss = acc[i][0][r] * a0 + acc[i][1][r] * a1;
            float sd = acc[i][0][r] * d0 + acc[i][1][r] * d1;
#pragma unroll
            for (int m = 1; m <= 8; m <<= 1) {
                ss += __shfl_xor(ss, m, 64);
                sd += __shfl_xor(sd, m, 64);
            }
            if (cq == 0) {
                int row = i * 16 + rq * 4 + r;
                sred[wave * 64 + row] = ss;
                dred[wave * 64 + row] = sd;
            }
        }
    __syncthreads();
    if (tid < 64) {
        float ss = sred[tid] + sred[64 + tid] + sred[128 + tid] + sred[192 + tid];
        float sd = dred[tid] + dred[64 + tid] + dred[128 + tid] + dred[192 + tid];
        ssrc[(size_t)(row0 + tid) * SH + head] = ss;
        sdst[(size_t)(row0 + tid) * SH + head] = sd;
    }
}

// ---------------- fused softmax + aggregation, layer 1/2 (H=4) ----------------
// 256 thr = 4 waves = 4 nodes (1 wave/node, no barriers). Inline logits from
// L2-resident ssrc4. Softmax in registers (deg<=64 fast path); alpha/src
// stashed in wave-private LDS for broadcast; gather unrolled 4-wide.
// Head-mean via xor16/32 shuffles; +bias, ELU, BN -> bf16.

__global__ __launch_bounds__(256) void agg4_kernel(const int* __restrict__ offs,
                                                   const int* __restrict__ csr,
                                                   const unsigned short* __restrict__ hbuf,
                                                   const float4* __restrict__ ssrc4,
                                                   const float4* __restrict__ sdst4,
                                                   const float* __restrict__ bias,
                                                   const float* __restrict__ bng,
                                                   const float* __restrict__ bnb,
                                                   const float* __restrict__ bnm,
                                                   const float* __restrict__ bnv,
                                                   unsigned short* __restrict__ outb) {
    __shared__ alignas(16) float aload[4][64][4];
    __shared__ int sload[4][64];

    int wave = threadIdx.x >> 6, lane = threadIdx.x & 63;
    int d = blockIdx.x * 4 + wave;
    int off = offs[d];
    int deg = offs[d + 1] - off;
    int hh = lane >> 4;
    float4 sdv = sdst4[d];
    float acc[8] = {};

    if (deg <= 64) {
        int sreg = 0;
        float4 ev;
        if (lane < deg) {
            sreg = csr[off + lane];
            float4 es = ssrc4[sreg];
            ev.x = es.x + sdv.x; ev.x = ev.x > 0.f ? ev.x : 0.2f * ev.x;
            ev.y = es.y + sdv.y; ev.y = ev.y > 0.f ? ev.y : 0.2f * ev.y;
            ev.z = es.z + sdv.z; ev.z = ev.z > 0.f ? ev.z : 0.2f * ev.z;
            ev.w = es.w + sdv.w; ev.w = ev.w > 0.f ? ev.w : 0.2f * ev.w;
        } else { ev.x = ev.y = ev.z = ev.w = -1e30f; }
        float4 mx = ev;
#pragma unroll
        for (int m = 32; m >= 1; m >>= 1) {
            mx.x = fmaxf(mx.x, __shfl_xor(mx.x, m, 64));
            mx.y = fmaxf(mx.y, __shfl_xor(mx.y, m, 64));
            mx.z = fmaxf(mx.z, __shfl_xor(mx.z, m, 64));
            mx.w = fmaxf(mx.w, __shfl_xor(mx.w, m, 64));
        }
        float4 p;
        p.x = (lane < deg) ? __expf(ev.x - mx.x) : 0.f;
        p.y = (lane < deg) ? __expf(ev.y - mx.y) : 0.f;
        p.z = (lane < deg) ? __expf(ev.z - mx.z) : 0.f;
        p.w = (lane < deg) ? __expf(ev.w - mx.w) : 0.f;
        float4 z = p;
#pragma unroll
        for (int m = 32; m >= 1; m >>= 1) {
            z.x += __shfl_xor(z.x, m, 64);
            z.y += __shfl_xor(z.y, m, 64);
            z.z += __shfl_xor(z.z, m, 64);
            z.w += __shfl_xor(z.w, m, 64);
        }
        float4 alpha;
        alpha.x = p.x / (z.x + 1e-16f);
        alpha.y = p.y / (z.y + 1e-16f);
        alpha.z = p.z / (z.z + 1e-16f);
        alpha.w = p.w / (z.w + 1e-16f);

        *(float4*)&aload[wave][lane][0] = alpha;
        sload[wave][lane] = sreg;
        // wave-private LDS slice: no __syncthreads needed (compiler emits lgkmcnt wait)

        int j = 0;
        for (; j + 3 < deg; j += 4) {
            int s0 = sload[wave][j],     s1 = sload[wave][j + 1];
            int s2 = sload[wave][j + 2], s3 = sload[wave][j + 3];
            float a0 = aload[wave][j][hh],     a1 = aload[wave][j + 1][hh];
            float a2 = aload[wave][j + 2][hh], a3 = aload[wave][j + 3][hh];
            bfx8 v0 = *(const bfx8*)(hbuf + (size_t)s0 * 512 + lane * 8);
            bfx8 v1 = *(const bfx8*)(hbuf + (size_t)s1 * 512 + lane * 8);
            bfx8 v2 = *(const bfx8*)(hbuf + (size_t)s2 * 512 + lane * 8);
            bfx8 v3 = *(const bfx8*)(hbuf + (size_t)s3 * 512 + lane * 8);
#pragma unroll
            for (int i = 0; i < 8; i++)
                acc[i] += a0 * bf2f(v0[i]) + a1 * bf2f(v1[i]) +
                          a2 * bf2f(v2[i]) + a3 * bf2f(v3[i]);
        }
        for (; j < deg; j++) {
            int s = sload[wave][j];
            float a = aload[wave][j][hh];
            bfx8 hv = *(const bfx8*)(hbuf + (size_t)s * 512 + lane * 8);
#pragma unroll
            for (int i = 0; i < 8; i++) acc[i] += a * bf2f(hv[i]);
        }
    } else {
        // generic fallback (rare): inline logits, per-edge recompute
        float4 mx; mx.x = mx.y = mx.z = mx.w = -1e30f;
        for (int j = lane; j < deg; j += 64) {
            int s = csr[off + j];
            float4 es = ssrc4[s];
            float4 e;
            e.x = es.x + sdv.x; e.x = e.x > 0.f ? e.x : 0.2f * e.x;
            e.y = es.y + sdv.y; e.y = e.y > 0.f ? e.y : 0.2f * e.y;
            e.z = es.z + sdv.z; e.z = e.z > 0.f ? e.z : 0.2f * e.z;
            e.w = es.w + sdv.w; e.w = e.w > 0.f ? e.w : 0.2f * e.w;
            mx.x = fmaxf(mx.x, e.x); mx.y = fmaxf(mx.y, e.y);
            mx.z = fmaxf(mx.z, e.z); mx.w = fmaxf(mx.w, e.w);
        }
#pragma unroll
        for (int m = 32; m >= 1; m >>= 1) {
            mx.x = fmaxf(mx.x, __shfl_xor(mx.x, m, 64));
            mx.y = fmaxf(mx.y, __shfl_xor(mx.y, m, 64));
            mx.z = fmaxf(mx.z, __shfl_xor(mx.z, m, 64));
            mx.w = fmaxf(mx.w, __shfl_xor(mx.w, m, 64));
        }
        float4 z; z.x = z.y = z.z = z.w = 0.f;
        for (int j = lane; j < deg; j += 64) {
            int s = csr[off + j];
            float4 es = ssrc4[s];
            float4 e;
            e.x = es.x + sdv.x; e.x = e.x > 0.f ? e.x : 0.2f * e.x;
            e.y = es.y + sdv.y; e.y = e.y > 0.f ? e.y : 0.2f * e.y;
            e.z = es.z + sdv.z; e.z = e.z > 0.f ? e.z : 0.2f * e.z;
            e.w = es.w + sdv.w; e.w = e.w > 0.f ? e.w : 0.2f * e.w;
            z.x += __expf(e.x - mx.x); z.y += __expf(e.y - mx.y);
            z.z += __expf(e.z - mx.z); z.w += __expf(e.w - mx.w);
        }
#pragma unroll
        for (int m = 32; m >= 1; m >>= 1) {
            z.x += __shfl_xor(z.x, m, 64);
            z.y += __shfl_xor(z.y, m, 64);
            z.z += __shfl_xor(z.z, m, 64);
            z.w += __shfl_xor(z.w, m, 64);
        }
        float mc = hh == 0 ? mx.x : hh == 1 ? mx.y : hh == 2 ? mx.z : mx.w;
        float zc = hh == 0 ? z.x : hh == 1 ? z.y : hh == 2 ? z.z : z.w;
        float ic = 1.f / (zc + 1e-16f);
        float sdc = hh == 0 ? sdv.x : hh == 1 ? sdv.y : hh == 2 ? sdv.z : sdv.w;
        for (int j = 0; j < deg; j++) {
            int s = csr[off + j];
            float4 es = ssrc4[s];
            float ec = hh == 0 ? es.x : hh == 1 ? es.y : hh == 2 ? es.z : es.w;
            ec += sdc; ec = ec > 0.f ? ec : 0.2f * ec;
            float a = __expf(ec - mc) * ic;
            bfx8 hv = *(const bfx8*)(hbuf + (size_t)s * 512 + lane * 8);
#pragma unroll
            for (int i = 0; i < 8; i++) acc[i] += a * bf2f(hv[i]);
        }
    }

    // head-mean: channel g=(lane&15) over lanes g, g+16, g+32, g+48
#pragma unroll
    for (int i = 0; i < 8; i++) {
        acc[i] += __shfl_xor(acc[i], 16, 64);
        acc[i] += __shfl_xor(acc[i], 32, 64);
    }
    if (lane < 16) {
        int c0 = lane * 8;
        bfx8 o;
#pragma unroll
        for (int i = 0; i < 8; i++) {
            int c = c0 + i;
            float v = acc[i] * 0.25f + bias[c];
            v = v > 0.f ? v : (__expf(v) - 1.0f);
            float sc = bng[c] * rsqrtf(bnv[c] + 1e-5f);
            v = (v - bnm[c]) * sc + bnb[c];
            o[i] = f2bf(v);
        }
        *(bfx8*)(outb + (size_t)d * 128 + c0) = o;
    }
}

// ---------------- fused softmax + aggregation, layer 3 (H=1) ----------------
// 1 wave/node, no barriers; wave-private LDS broadcast; half-wave edge split
// with unroll-2; dense fp32 h3out write (no atomics).

__global__ __launch_bounds__(256) void agg1_kernel(const int* __restrict__ offs,
                                                   const int* __restrict__ csr,
                                                   const unsigned short* __restrict__ hbuf1,
                                                   const float* __restrict__ ssrc1,
                                                   const float* __restrict__ sdst1,
                                                   const float* __restrict__ bias,
                                                   float* __restrict__ h3out) {
    __shared__ float aload[4][64];
    __shared__ int sload[4][64];
    int wave = threadIdx.x >> 6, lane = threadIdx.x & 63;
    int d = blockIdx.x * 4 + wave;
    int off = offs[d];
    int deg = offs[d + 1] - off;
    int half = lane >> 5, li = lane & 31;
    float sdv = sdst1[d];
    float acc[4] = {};

    if (deg <= 64) {
        float ev = -1e30f; int sreg = 0;
        if (lane < deg) {
            sreg = csr[off + lane];
            ev = ssrc1[sreg] + sdv;
            ev = ev > 0.f ? ev : 0.2f * ev;
        }
        float mx = ev;
#pragma unroll
        for (int m = 32; m >= 1; m >>= 1) mx = fmaxf(mx, __shfl_xor(mx, m, 64));
        float p = (lane < deg) ? __expf(ev - mx) : 0.f;
        float z = p;
#pragma unroll
        for (int m = 32; m >= 1; m >>= 1) z += __shfl_xor(z, m, 64);
        aload[wave][lane] = p / (z + 1e-16f);
        sload[wave][lane] = sreg;

        int j = half;
        for (; j + 2 < deg; j += 4) {
            int s0 = sload[wave][j], s1 = sload[wave][j + 2];
            float a0 = aload[wave][j], a1 = aload[wave][j + 2];
            bfx4 v0 = *(const bfx4*)(hbuf1 + (size_t)s0 * 128 + li * 4);
            bfx4 v1 = *(const bfx4*)(hbuf1 + (size_t)s1 * 128 + li * 4);
#pragma unroll
            for (int i = 0; i < 4; i++)
                acc[i] += a0 * bf2f(v0[i]) + a1 * bf2f(v1[i]);
        }
        for (; j < deg; j += 2) {
            int s = sload[wave][j];
            float a = aload[wave][j];
            bfx4 hv = *(const bfx4*)(hbuf1 + (size_t)s * 128 + li * 4);
#pragma unroll
            for (int i = 0; i < 4; i++) acc[i] += a * bf2f(hv[i]);
        }
    } else {
        float mx = -1e30f;
        for (int j = lane; j < deg; j += 64) {
            float e = ssrc1[csr[off + j]] + sdv;
            e = e > 0.f ? e : 0.2f * e;
            mx = fmaxf(mx, e);
        }
#pragma unroll
        for (int m = 32; m >= 1; m >>= 1) mx = fmaxf(mx, __shfl_xor(mx, m, 64));
        float z = 0.f;
        for (int j = lane; j < deg; j += 64) {
            float e = ssrc1[csr[off + j]] + sdv;
            e = e > 0.f ? e : 0.2f * e;
            z += __expf(e - mx);
        }
#pragma unroll
        for (int m = 32; m >= 1; m >>= 1) z += __shfl_xor(z, m, 64);
        float inv = 1.f / (z + 1e-16f);
        for (int j = half; j < deg; j += 2) {
            int s = csr[off + j];
            float e = ssrc1[s] + sdv;
            e = e > 0.f ? e : 0.2f * e;
            float a = __expf(e - mx) * inv;
            bfx4 hv = *(const bfx4*)(hbuf1 + (size_t)s * 128 + li * 4);
#pragma unroll
            for (int i = 0; i < 4; i++) acc[i] += a * bf2f(hv[i]);
        }
    }

#pragma unroll
    for (int i = 0; i < 4; i++) acc[i] += __shfl_xor(acc[i], 32, 64);
    if (lane < 32) {
        float4 o;
        o.x = acc[0] + bias[li * 4];
        o.y = acc[1] + bias[li * 4 + 1];
        o.z = acc[2] + bias[li * 4 + 2];
        o.w = acc[3] + bias[li * 4 + 3];
        *(float4*)(h3out + (size_t)d * 128 + li * 4) = o;
    }
}

// ---------------- grouped mean-pool (batch sorted; binary search) ----------------

__global__ __launch_bounds__(256) void pool_kernel(const float* __restrict__ h3,
                                                   const int* __restrict__ batch,
                                                   float* __restrict__ out) {
    __shared__ float red[256];
    int g = blockIdx.x;
    int t = threadIdx.x;
    int lo = 0, n = N_NODES;
    while (n > 0) { int s = n >> 1; if (batch[lo + s] < g) { lo += s + 1; n -= s + 1; } else n = s; }
    int hi = lo; n = N_NODES - lo;
    while (n > 0) { int s = n >> 1; if (batch[hi + s] < g + 1) { hi += s + 1; n -= s + 1; } else n = s; }
    int c = t & 127;
    float acc = 0.f;
    for (int r = lo + (t >> 7); r < hi; r += 2)
        acc += h3[(size_t)r * 128 + c];
    red[t] = acc;
    __syncthreads();
    if (t < 128)
        out[(size_t)g * 128 + t] = (red[t] + red[t + 128]) / fmaxf((float)(hi - lo), 1.0f);
}

// ---------------- host ----------------

extern "C" void kernel_launch(void* const* d_in, const int* in_sizes, int n_in,
                              void* d_out, int out_size, void* d_ws, size_t ws_size,
                              hipStream_t stream) {
    const float* x    = (const float*)d_in[0];
    const int* src    = (const int*)d_in[1];
    const int* dst    = (const int*)d_in[2];
    const int* batch  = (const int*)d_in[3];
    const float* W1   = (const float*)d_in[4];
    const float* as1  = (const float*)d_in[5];
    const float* ad1  = (const float*)d_in[6];
    const float* b1   = (const float*)d_in[7];
    const float* g1   = (const float*)d_in[8];
    const float* be1  = (const float*)d_in[9];
    const float* m1   = (const float*)d_in[10];
    const float* v1   = (const float*)d_in[11];
    const float* W2   = (const float*)d_in[12];
    const float* as2  = (const float*)d_in[13];
    const float* ad2  = (const float*)d_in[14];
    const float* b2   = (const float*)d_in[15];
    const float* g2   = (const float*)d_in[16];
    const float* be2  = (const float*)d_in[17];
    const float* m2   = (const float*)d_in[18];
    const float* v2   = (const float*)d_in[19];
    const float* W3   = (const float*)d_in[20];
    const float* as3  = (const float*)d_in[21];
    const float* ad3  = (const float*)d_in[22];
    const float* b3   = (const float*)d_in[23];
    float* out = (float*)d_out;

    char* w = (char*)d_ws;
    size_t o = 0;
    auto alloc = [&](size_t bytes) -> void* {
        void* p = w + o;
        o += (bytes + 255) & ~(size_t)255;
        return p;
    };
    int* deg     = (int*)alloc((size_t)N_NODES * 4);
    int* offs    = (int*)alloc((size_t)(N_NODES + 1) * 4);
    int* cursor  = (int*)alloc((size_t)N_NODES * 4);
    int* csr     = (int*)alloc((size_t)ETOT * 4);
    float* ssrc  = (float*)alloc((size_t)N_NODES * NHEAD * 4);
    float* sdst  = (float*)alloc((size_t)N_NODES * NHEAD * 4);
    float* h3out = (float*)alloc((size_t)N_NODES * 128 * 4);
    unsigned short* hbuf = (unsigned short*)alloc((size_t)N_NODES * 512 * 2);
    unsigned short* xbuf = (unsigned short*)alloc((size_t)N_NODES * 128 * 2);
    unsigned short* W1t  = (unsigned short*)alloc((size_t)512 * 256 * 2);
    unsigned short* W2t  = (unsigned short*)alloc((size_t)512 * 128 * 2);
    unsigned short* W3t  = (unsigned short*)alloc((size_t)128 * 128 * 2);

    (void)hipMemsetAsync(deg, 0, (size_t)N_NODES * 4, stream);

    // CSR build
    count_kernel<<<(ETOT + 255) / 256, 256, 0, stream>>>(dst, deg);
    scan_kernel<<<1, 1024, 0, stream>>>(deg, offs, cursor);
    fill_kernel<<<(ETOT + 255) / 256, 256, 0, stream>>>(src, dst, cursor, csr);

    // weight prep
    transpose_w_kernel<<<(256 * 512 + 255) / 256, 256, 0, stream>>>(W1, W1t, 256, 512);
    transpose_w_kernel<<<(128 * 512 + 255) / 256, 256, 0, stream>>>(W2, W2t, 128, 512);
    transpose_w_kernel<<<(128 * 128 + 255) / 256, 256, 0, stream>>>(W3, W3t, 128, 128);

    // ----- layer 1 -----
    mfma_gemm_kernel<256, 512, true><<<dim3(N_NODES / 64, 4), 256, 0, stream>>>(
        x, W1t, hbuf, as1, ad1, ssrc, sdst);
    agg4_kernel<<<N_NODES / 4, 256, 0, stream>>>(offs, csr, hbuf, (const float4*)ssrc,
                                                 (const float4*)sdst, b1, g1, be1, m1, v1, xbuf);

    // ----- layer 2 -----
    mfma_gemm_kernel<128, 512, false><<<dim3(N_NODES / 64, 4), 256, 0, stream>>>(
        xbuf, W2t, hbuf, as2, ad2, ssrc, sdst);
    agg4_kernel<<<N_NODES / 4, 256, 0, stream>>>(offs, csr, hbuf, (const float4*)ssrc,
                                                 (const float4*)sdst, b2, g2, be2, m2, v2, xbuf);

    // ----- layer 3 -----
    mfma_gemm_kernel<128, 128, false><<<dim3(N_NODES / 64, 1), 256, 0, stream>>>(
        xbuf, W3t, hbuf, as3, ad3, ssrc, sdst);
    agg1_kernel<<<N_NODES / 4, 256, 0, stream>>>(offs, csr, hbuf, ssrc, sdst, b3, h3out);

    // ----- grouped mean pool -----
    pool_kernel<<<NG, 256, 0, stream>>>(h3out, batch, out);
}